// Round 1
// baseline (732.963 us; speedup 1.0000x reference)
//
#include <hip/hip_runtime.h>
#include <math.h>

#define TOK 2048
#define NDIM 1024

typedef __attribute__((ext_vector_type(4))) float f32x4;
typedef __attribute__((ext_vector_type(8))) short s16x8;
typedef __attribute__((ext_vector_type(4))) short s16x4;

__device__ __forceinline__ short f2bf(float x) {
  unsigned int u = __builtin_bit_cast(unsigned int, x);
  unsigned int r = (u + 0x7fffu + ((u >> 16) & 1u)) >> 16;
  return (short)r;
}
__device__ __forceinline__ float bf2f(short s) {
  unsigned int u = ((unsigned int)(unsigned short)s) << 16;
  return __builtin_bit_cast(float, u);
}
__device__ __forceinline__ void gload_lds16(const void* g, void* l) {
  __builtin_amdgcn_global_load_lds((const __attribute__((address_space(1))) void*)g,
                                   (__attribute__((address_space(3))) void*)l, 16, 0, 0);
}

// ---------------- LayerNorm: fp32 in -> bf16 out ----------------
__global__ __launch_bounds__(256)
void ln_k(const float* __restrict__ x, const float* __restrict__ g,
          const float* __restrict__ bb, short* __restrict__ out)
{
  const int row = blockIdx.x, tid = threadIdx.x;
  const f32x4 xv = *(const f32x4*)(x + (size_t)row * NDIM + tid * 4);
  float s = xv[0] + xv[1] + xv[2] + xv[3];
  float s2 = xv[0]*xv[0] + xv[1]*xv[1] + xv[2]*xv[2] + xv[3]*xv[3];
  #pragma unroll
  for (int m = 1; m < 64; m <<= 1) { s += __shfl_xor(s, m); s2 += __shfl_xor(s2, m); }
  __shared__ float red[8];
  const int w = tid >> 6, l = tid & 63;
  if (l == 0) { red[w] = s; red[4 + w] = s2; }
  __syncthreads();
  s = red[0] + red[1] + red[2] + red[3];
  s2 = red[4] + red[5] + red[6] + red[7];
  const float mean = s * (1.0f / NDIM);
  const float var = s2 * (1.0f / NDIM) - mean * mean;
  const float rstd = rsqrtf(var + 1e-5f);
  const f32x4 gv = *(const f32x4*)(g + tid * 4);
  const f32x4 bv = *(const f32x4*)(bb + tid * 4);
  s16x4 ov;
  #pragma unroll
  for (int j = 0; j < 4; ++j) ov[j] = f2bf((xv[j] - mean) * rstd * gv[j] + bv[j]);
  *(s16x4*)(out + (size_t)row * NDIM + tid * 4) = ov;
}

// ---------------- Gate: fp32 LN recompute + gate/coef softmax + buckets ----------------
__global__ __launch_bounds__(256)
void gate_k(const float* __restrict__ x1, const float* __restrict__ g,
            const float* __restrict__ bb, const float* __restrict__ gw,
            const float* __restrict__ cw, const float* __restrict__ cb,
            int* __restrict__ counts, int* __restrict__ bucket,
            float* __restrict__ gs, float* __restrict__ c1o)
{
  const int tid = threadIdx.x, l = tid & 63, w = tid >> 6;
  const int t = blockIdx.x * 4 + w;
  f32x4 xv[4];
  #pragma unroll
  for (int it = 0; it < 4; ++it)
    xv[it] = *(const f32x4*)(x1 + (size_t)t * NDIM + it * 256 + l * 4);
  float s = 0.f, s2 = 0.f;
  #pragma unroll
  for (int it = 0; it < 4; ++it)
    #pragma unroll
    for (int j = 0; j < 4; ++j) { s += xv[it][j]; s2 += xv[it][j] * xv[it][j]; }
  #pragma unroll
  for (int m = 1; m < 64; m <<= 1) { s += __shfl_xor(s, m); s2 += __shfl_xor(s2, m); }
  const float mean = s * (1.0f / NDIM);
  const float rstd = rsqrtf(s2 * (1.0f / NDIM) - mean * mean + 1e-5f);
  float acc[10];
  #pragma unroll
  for (int j = 0; j < 10; ++j) acc[j] = 0.f;
  #pragma unroll
  for (int it = 0; it < 4; ++it) {
    #pragma unroll
    for (int j = 0; j < 4; ++j) {
      const int d0 = it * 256 + l * 4 + j;
      const float xn = (xv[it][j] - mean) * rstd * g[d0] + bb[d0];
      const f32x4 g0 = *(const f32x4*)(gw + (size_t)d0 * 8);
      const f32x4 g1 = *(const f32x4*)(gw + (size_t)d0 * 8 + 4);
      #pragma unroll
      for (int q = 0; q < 4; ++q) { acc[q] += xn * g0[q]; acc[4 + q] += xn * g1[q]; }
      acc[8] += xn * cw[d0 * 2]; acc[9] += xn * cw[d0 * 2 + 1];
    }
  }
  #pragma unroll
  for (int j = 0; j < 10; ++j)
    #pragma unroll
    for (int m = 1; m < 64; m <<= 1) acc[j] += __shfl_xor(acc[j], m);
  if (l == 0) {
    int best = 0; float mx = acc[0];
    #pragma unroll
    for (int e = 1; e < 8; ++e) if (acc[e] > mx) { mx = acc[e]; best = e; }
    float se = 0.f;
    #pragma unroll
    for (int e = 0; e < 8; ++e) se += __expf(acc[e] - mx);
    const float gate_val = 1.0f / se;
    const float l0 = acc[8] + cb[0], l1 = acc[9] + cb[1];
    const float cmx = fmaxf(l0, l1);
    const float e0 = __expf(l0 - cmx), e1 = __expf(l1 - cmx);
    const float inv = 1.0f / (e0 + e1);
    const int pos = atomicAdd(&counts[best], 1);
    bucket[best * TOK + pos] = t;
    gs[t] = gate_val * e0 * inv;
    c1o[t] = e1 * inv;
  }
}

// ---------------- Generic bf16 MFMA GEMM, 128x128 tile, BK=64 ----------------
// A: [M,K] bf16 (optionally row-gathered), B: [K,N] fp32 (inline cvt+transpose)
// EPI: 0=store bf16, 1=GELU->bf16, 2=resid fp32 (x + acc + bias),
//      3=moe scale fp32 ((acc+bias)*sA[row]), 4=final (resid + aux + (acc+bias)*sB[row])
struct GemmP {
  const short* A; const float* B; const float* bias;
  float* outf; short* outh;
  const float* resid; const float* aux; const float* sA; const float* sB;
  const int* bucket; const int* counts;
  int N, K, ntiles;
};

template<int EPI, bool GATHER>
__global__ __launch_bounds__(256, 2)
void gemm_k(GemmP p)
{
  __shared__ short Al[8192];  // [chunk8][row128][8] linear, 16KB
  __shared__ short Bl[8192];  // [n128][k64] swizzled,   16KB
  const int tid = threadIdx.x;
  const int l = tid & 63, w = tid >> 6;
  const int wr = w >> 1, wc = w & 1;
  const int mt = blockIdx.x / p.ntiles;
  const int nt = blockIdx.x % p.ntiles;
  const int K = p.K, N = p.N;

  int cnt = TOK;
  const short* Abase = p.A;
  const float* Bbase = p.B;
  const float* bias = p.bias;
  const int* bucket = nullptr;
  if (GATHER) {
    const int e = blockIdx.y;
    cnt = p.counts[e];
    if (mt * 128 >= cnt) return;
    bucket = p.bucket + e * TOK;
    Bbase = p.B + (size_t)e * K * N;
    bias = p.bias + (size_t)e * N;
  }

  const short* aptr[4];
  #pragma unroll
  for (int i = 0; i < 4; ++i) {
    const int s = i * 256 + tid;
    const int c = s >> 7, r = s & 127;
    int row;
    if (GATHER) {
      const int bidx = mt * 128 + r;
      row = bucket[bidx < cnt ? bidx : mt * 128];
    } else row = mt * 128 + r;
    aptr[i] = Abase + (size_t)row * K + c * 8;
  }

  f32x4 acc[4][4] = {};
  const int nK = K >> 6;
  for (int kt = 0; kt < nK; ++kt) {
    #pragma unroll
    for (int i = 0; i < 4; ++i)
      gload_lds16(aptr[i] + kt * 64, (char*)Al + (i * 256 + (tid & 192)) * 16);
    #pragma unroll
    for (int i = 0; i < 4; ++i) {
      const int seg = i * 4 + w;
      const int kk = (seg & 7) * 8;
      const int nn = (seg >> 3) * 64;
      const float* bp = Bbase + (size_t)(kt * 64 + kk) * N + nt * 128 + nn + l;
      s16x8 pk;
      #pragma unroll
      for (int j = 0; j < 8; ++j) pk[j] = f2bf(bp[(size_t)j * N]);
      *(s16x8*)((char*)Bl + ((((nn + l) * 64 + kk) * 2) ^ ((l & 7) << 4))) = pk;
    }
    __syncthreads();
    #pragma unroll
    for (int ks = 0; ks < 2; ++ks) {
      s16x8 af[4], bfr[4];
      #pragma unroll
      for (int mf = 0; mf < 4; ++mf)
        af[mf] = *(const s16x8*)((char*)Al +
            ((ks * 4 + (l >> 4)) * 128 + wr * 64 + mf * 16 + (l & 15)) * 16);
      #pragma unroll
      for (int nf = 0; nf < 4; ++nf) {
        const int col = wc * 64 + nf * 16 + (l & 15);
        bfr[nf] = *(const s16x8*)((char*)Bl +
            (((col * 64 + ks * 32 + (l >> 4) * 8) * 2) ^ ((l & 7) << 4)));
      }
      #pragma unroll
      for (int mf = 0; mf < 4; ++mf)
        #pragma unroll
        for (int nf = 0; nf < 4; ++nf)
          acc[mf][nf] = __builtin_amdgcn_mfma_f32_16x16x32_bf16(af[mf], bfr[nf], acc[mf][nf], 0, 0, 0);
    }
    __syncthreads();
  }

  #pragma unroll
  for (int mf = 0; mf < 4; ++mf) {
    #pragma unroll
    for (int i = 0; i < 4; ++i) {
      const int rloc = wr * 64 + mf * 16 + (l >> 4) * 4 + i;
      int grow; bool valid = true;
      if (GATHER) {
        const int bidx = mt * 128 + rloc;
        valid = bidx < cnt;
        grow = valid ? bucket[bidx] : 0;
      } else grow = mt * 128 + rloc;
      float srow = 0.f;
      if (EPI == 3) srow = valid ? p.sA[grow] : 0.f;
      if (EPI == 4) srow = p.sB[grow];
      #pragma unroll
      for (int nf = 0; nf < 4; ++nf) {
        const int col = nt * 128 + wc * 64 + nf * 16 + (l & 15);
        const float v = acc[mf][nf][i] + bias[col];
        const size_t off = (size_t)grow * N + col;
        if (EPI == 0) { if (valid) p.outh[off] = f2bf(v); }
        else if (EPI == 1) {
          const float gv = 0.5f * v * (1.0f + erff(v * 0.70710678f));
          if (valid) p.outh[off] = f2bf(gv);
        }
        else if (EPI == 2) { p.outf[off] = p.resid[off] + v; }
        else if (EPI == 3) { if (valid) p.outf[off] = v * srow; }
        else if (EPI == 4) { p.outf[off] = p.resid[off] + p.aux[off] + v * srow; }
      }
    }
  }
}

// ---------------- Flash attention: 4 waves x 16 q-rows, KV tiles of 64 ----------------
__global__ __launch_bounds__(256, 2)
void attn_k(const short* __restrict__ qkv, short* __restrict__ ctx)
{
  __shared__ short Klds[64 * 64];      // [kv][dh] swizzled (pre-swizzled source)
  __shared__ short Vlds[64 * 64];      // [dh][kv] swizzled (transposed)
  __shared__ short Plds[4 * 16 * 64];  // per-wave [q16][kv64] swizzled
  const int tid = threadIdx.x, l = tid & 63, w = tid >> 6;
  const int qt = blockIdx.x;
  const int bh = blockIdx.y;
  const int b = bh >> 4, h = bh & 15;
  const size_t tbase = (size_t)b * 1024;

  const int sq = qt * 64 + w * 16 + (l & 15);
  s16x8 qf[2];
  #pragma unroll
  for (int ks = 0; ks < 2; ++ks)
    qf[ks] = *(const s16x8*)(qkv + (tbase + sq) * 3072 + h * 64 + ks * 32 + (l >> 4) * 8);

  f32x4 o[4] = {};
  float mrow[4], lrow[4];
  #pragma unroll
  for (int i = 0; i < 4; ++i) { mrow[i] = -1e30f; lrow[i] = 0.f; }

  for (int kt = 0; kt < 16; ++kt) {
    #pragma unroll
    for (int i = 0; i < 2; ++i) {
      const int s = i * 256 + tid;
      const int r = s >> 3, c = s & 7, csrc = c ^ (r & 7);
      const short* gsrc = qkv + (tbase + kt * 64 + r) * 3072 + 1024 + h * 64 + csrc * 8;
      gload_lds16(gsrc, (char*)Klds + (i * 256 + (tid & 192)) * 16);
    }
    #pragma unroll
    for (int i = 0; i < 2; ++i) {
      const int kv0 = (i * 4 + w) * 8;
      s16x8 vv;
      #pragma unroll
      for (int j = 0; j < 8; ++j)
        vv[j] = qkv[(tbase + kt * 64 + kv0 + j) * 3072 + 2048 + h * 64 + l];
      *(s16x8*)((char*)Vlds + ((l * 128 + kv0 * 2) ^ ((l & 7) << 4))) = vv;
    }
    __syncthreads();

    f32x4 sv[4];
    #pragma unroll
    for (int nf = 0; nf < 4; ++nf) {
      f32x4 a = {0.f, 0.f, 0.f, 0.f};
      const int kv = nf * 16 + (l & 15);
      #pragma unroll
      for (int ks = 0; ks < 2; ++ks) {
        const s16x8 kb = *(const s16x8*)((char*)Klds +
            ((kv * 128 + (ks * 32 + (l >> 4) * 8) * 2) ^ ((kv & 7) << 4)));
        a = __builtin_amdgcn_mfma_f32_16x16x32_bf16(qf[ks], kb, a, 0, 0, 0);
      }
      sv[nf] = a * 0.125f;
    }
    float sc[4], ps[4];
    #pragma unroll
    for (int i = 0; i < 4; ++i) {
      float m = fmaxf(fmaxf(sv[0][i], sv[1][i]), fmaxf(sv[2][i], sv[3][i]));
      #pragma unroll
      for (int msk = 1; msk < 16; msk <<= 1) m = fmaxf(m, __shfl_xor(m, msk));
      const float mn = fmaxf(mrow[i], m);
      sc[i] = __expf(mrow[i] - mn);
      mrow[i] = mn;
      ps[i] = 0.f;
    }
    #pragma unroll
    for (int nf = 0; nf < 4; ++nf)
      #pragma unroll
      for (int i = 0; i < 4; ++i) {
        const float pp = __expf(sv[nf][i] - mrow[i]);
        sv[nf][i] = pp;
        ps[i] += pp;
      }
    #pragma unroll
    for (int i = 0; i < 4; ++i) {
      #pragma unroll
      for (int msk = 1; msk < 16; msk <<= 1) ps[i] += __shfl_xor(ps[i], msk);
      lrow[i] = lrow[i] * sc[i] + ps[i];
    }
    #pragma unroll
    for (int nf = 0; nf < 4; ++nf)
      #pragma unroll
      for (int i = 0; i < 4; ++i) o[nf][i] *= sc[i];

    char* pw = (char*)Plds + w * 2048;
    #pragma unroll
    for (int nf = 0; nf < 4; ++nf)
      #pragma unroll
      for (int i = 0; i < 4; ++i) {
        const int q = (l >> 4) * 4 + i;
        *(short*)(pw + ((q * 128 + (nf * 16 + (l & 15)) * 2) ^ ((q & 7) << 4))) = f2bf(sv[nf][i]);
      }
    __syncthreads();
    #pragma unroll
    for (int ks = 0; ks < 2; ++ks) {
      const s16x8 pa = *(const s16x8*)(pw +
          (((l & 15) * 128 + (ks * 32 + (l >> 4) * 8) * 2) ^ ((l & 7) << 4)));
      #pragma unroll
      for (int nf = 0; nf < 4; ++nf) {
        const int dh = nf * 16 + (l & 15);
        const s16x8 vb = *(const s16x8*)((char*)Vlds +
            ((dh * 128 + (ks * 32 + (l >> 4) * 8) * 2) ^ ((dh & 7) << 4)));
        o[nf] = __builtin_amdgcn_mfma_f32_16x16x32_bf16(pa, vb, o[nf], 0, 0, 0);
      }
    }
    __syncthreads();
  }
  #pragma unroll
  for (int i = 0; i < 4; ++i) {
    const float inv = 1.0f / lrow[i];
    const size_t t = tbase + qt * 64 + w * 16 + (l >> 4) * 4 + i;
    #pragma unroll
    for (int nf = 0; nf < 4; ++nf)
      ctx[t * 1024 + h * 64 + nf * 16 + (l & 15)] = f2bf(o[nf][i] * inv);
  }
}

extern "C" void kernel_launch(void* const* d_in, const int* in_sizes, int n_in,
                              void* d_out, int out_size, void* d_ws, size_t ws_size,
                              hipStream_t stream)
{
  const float* x    = (const float*)d_in[0];
  const float* ln1g = (const float*)d_in[1];
  const float* ln1b = (const float*)d_in[2];
  const float* Wqkv = (const float*)d_in[3];
  const float* bqkv = (const float*)d_in[4];
  const float* Wo   = (const float*)d_in[5];
  const float* bo   = (const float*)d_in[6];
  const float* ln2g = (const float*)d_in[7];
  const float* ln2b = (const float*)d_in[8];
  const float* gw   = (const float*)d_in[9];
  const float* W1   = (const float*)d_in[10];
  const float* b1   = (const float*)d_in[11];
  const float* W2   = (const float*)d_in[12];
  const float* b2   = (const float*)d_in[13];
  const float* rW1  = (const float*)d_in[14];
  const float* rb1  = (const float*)d_in[15];
  const float* rW2  = (const float*)d_in[16];
  const float* rb2  = (const float*)d_in[17];
  const float* cw   = (const float*)d_in[18];
  const float* cb   = (const float*)d_in[19];
  float* out = (float*)d_out;

  char* ws = (char*)d_ws;
  const size_t MB = 1024 * 1024;
  short* xn1    = (short*)(ws + 0);          // 4 MB
  short* qkv    = (short*)(ws + 4 * MB);     // 12 MB
  short* he     = (short*)(ws + 4 * MB);     // 16 MB (aliases qkv+ctx, dead by then)
  short* ctx    = (short*)(ws + 16 * MB);    // 4 MB
  float* x1     = (float*)(ws + 20 * MB);    // 8 MB
  short* xn2    = (short*)(ws + 28 * MB);    // 4 MB
  short* hr     = (short*)(ws + 32 * MB);    // 16 MB
  float* moe    = (float*)(ws + 48 * MB);    // 8 MB
  int*   counts = (int*)(ws + 56 * MB);
  int*   bucket = (int*)(ws + 56 * MB + 256);
  float* gs     = (float*)(ws + 56 * MB + 256 + 64 * 1024);
  float* c1     = (float*)(ws + 56 * MB + 256 + 64 * 1024 + 8192);

  hipMemsetAsync(counts, 0, 8 * sizeof(int), stream);

  ln_k<<<TOK, 256, 0, stream>>>(x, ln1g, ln1b, xn1);

  GemmP p{};
  p.A = xn1; p.B = Wqkv; p.bias = bqkv; p.outh = qkv; p.N = 3072; p.K = 1024; p.ntiles = 24;
  gemm_k<0, false><<<dim3(16 * 24), 256, 0, stream>>>(p);

  attn_k<<<dim3(16, 32), 256, 0, stream>>>(qkv, ctx);

  p = GemmP{};
  p.A = ctx; p.B = Wo; p.bias = bo; p.outf = x1; p.resid = x; p.N = 1024; p.K = 1024; p.ntiles = 8;
  gemm_k<2, false><<<dim3(16 * 8), 256, 0, stream>>>(p);

  ln_k<<<TOK, 256, 0, stream>>>(x1, ln2g, ln2b, xn2);
  gate_k<<<TOK / 4, 256, 0, stream>>>(x1, ln2g, ln2b, gw, cw, cb, counts, bucket, gs, c1);

  p = GemmP{};
  p.A = xn2; p.B = W1; p.bias = b1; p.outh = he; p.N = 4096; p.K = 1024; p.ntiles = 32;
  p.bucket = bucket; p.counts = counts;
  gemm_k<1, true><<<dim3(16 * 32, 8), 256, 0, stream>>>(p);

  p = GemmP{};
  p.A = he; p.B = W2; p.bias = b2; p.outf = moe; p.sA = gs; p.N = 1024; p.K = 4096; p.ntiles = 8;
  p.bucket = bucket; p.counts = counts;
  gemm_k<3, true><<<dim3(16 * 8, 8), 256, 0, stream>>>(p);

  p = GemmP{};
  p.A = xn2; p.B = rW1; p.bias = rb1; p.outh = hr; p.N = 4096; p.K = 1024; p.ntiles = 32;
  gemm_k<1, false><<<dim3(16 * 32), 256, 0, stream>>>(p);

  p = GemmP{};
  p.A = hr; p.B = rW2; p.bias = rb2; p.outf = out; p.resid = x1; p.aux = moe; p.sB = c1;
  p.N = 1024; p.K = 4096; p.ntiles = 8;
  gemm_k<4, false><<<dim3(16 * 8), 256, 0, stream>>>(p);
}

// Round 2
// 598.590 us; speedup vs baseline: 1.2245x; 1.2245x over previous
//
#include <hip/hip_runtime.h>
#include <math.h>

#define TOK 2048
#define NDIM 1024

typedef __attribute__((ext_vector_type(4))) float f32x4;
typedef __attribute__((ext_vector_type(8))) short s16x8;
typedef __attribute__((ext_vector_type(4))) short s16x4;

__device__ __forceinline__ short f2bf(float x) {
  unsigned int u = __builtin_bit_cast(unsigned int, x);
  unsigned int r = (u + 0x7fffu + ((u >> 16) & 1u)) >> 16;
  return (short)r;
}
__device__ __forceinline__ void gload_lds16(const void* g, void* l) {
  __builtin_amdgcn_global_load_lds((const __attribute__((address_space(1))) void*)g,
                                   (__attribute__((address_space(3))) void*)l, 16, 0, 0);
}

// ---------------- LayerNorm: fp32 in -> bf16 out ----------------
__global__ __launch_bounds__(256)
void ln_k(const float* __restrict__ x, const float* __restrict__ g,
          const float* __restrict__ bb, short* __restrict__ out)
{
  const int row = blockIdx.x, tid = threadIdx.x;
  const f32x4 xv = *(const f32x4*)(x + (size_t)row * NDIM + tid * 4);
  float s = xv[0] + xv[1] + xv[2] + xv[3];
  float s2 = xv[0]*xv[0] + xv[1]*xv[1] + xv[2]*xv[2] + xv[3]*xv[3];
  #pragma unroll
  for (int m = 1; m < 64; m <<= 1) { s += __shfl_xor(s, m); s2 += __shfl_xor(s2, m); }
  __shared__ float red[8];
  const int w = tid >> 6, l = tid & 63;
  if (l == 0) { red[w] = s; red[4 + w] = s2; }
  __syncthreads();
  s = red[0] + red[1] + red[2] + red[3];
  s2 = red[4] + red[5] + red[6] + red[7];
  const float mean = s * (1.0f / NDIM);
  const float var = s2 * (1.0f / NDIM) - mean * mean;
  const float rstd = rsqrtf(var + 1e-5f);
  const f32x4 gv = *(const f32x4*)(g + tid * 4);
  const f32x4 bv = *(const f32x4*)(bb + tid * 4);
  s16x4 ov;
  #pragma unroll
  for (int j = 0; j < 4; ++j) ov[j] = f2bf((xv[j] - mean) * rstd * gv[j] + bv[j]);
  *(s16x4*)(out + (size_t)row * NDIM + tid * 4) = ov;
}

// ---------------- Gate: fp32 LN recompute + gate/coef softmax + buckets ----------------
__global__ __launch_bounds__(256)
void gate_k(const float* __restrict__ x1, const float* __restrict__ g,
            const float* __restrict__ bb, const float* __restrict__ gw,
            const float* __restrict__ cw, const float* __restrict__ cb,
            int* __restrict__ counts, int* __restrict__ bucket,
            float* __restrict__ gs, float* __restrict__ c1o)
{
  const int tid = threadIdx.x, l = tid & 63, w = tid >> 6;
  const int t = blockIdx.x * 4 + w;
  f32x4 xv[4];
  #pragma unroll
  for (int it = 0; it < 4; ++it)
    xv[it] = *(const f32x4*)(x1 + (size_t)t * NDIM + it * 256 + l * 4);
  float s = 0.f, s2 = 0.f;
  #pragma unroll
  for (int it = 0; it < 4; ++it)
    #pragma unroll
    for (int j = 0; j < 4; ++j) { s += xv[it][j]; s2 += xv[it][j] * xv[it][j]; }
  #pragma unroll
  for (int m = 1; m < 64; m <<= 1) { s += __shfl_xor(s, m); s2 += __shfl_xor(s2, m); }
  const float mean = s * (1.0f / NDIM);
  const float rstd = rsqrtf(s2 * (1.0f / NDIM) - mean * mean + 1e-5f);
  float acc[10];
  #pragma unroll
  for (int j = 0; j < 10; ++j) acc[j] = 0.f;
  #pragma unroll
  for (int it = 0; it < 4; ++it) {
    #pragma unroll
    for (int j = 0; j < 4; ++j) {
      const int d0 = it * 256 + l * 4 + j;
      const float xn = (xv[it][j] - mean) * rstd * g[d0] + bb[d0];
      const f32x4 g0 = *(const f32x4*)(gw + (size_t)d0 * 8);
      const f32x4 g1 = *(const f32x4*)(gw + (size_t)d0 * 8 + 4);
      #pragma unroll
      for (int q = 0; q < 4; ++q) { acc[q] += xn * g0[q]; acc[4 + q] += xn * g1[q]; }
      acc[8] += xn * cw[d0 * 2]; acc[9] += xn * cw[d0 * 2 + 1];
    }
  }
  #pragma unroll
  for (int j = 0; j < 10; ++j)
    #pragma unroll
    for (int m = 1; m < 64; m <<= 1) acc[j] += __shfl_xor(acc[j], m);
  if (l == 0) {
    int best = 0; float mx = acc[0];
    #pragma unroll
    for (int e = 1; e < 8; ++e) if (acc[e] > mx) { mx = acc[e]; best = e; }
    float se = 0.f;
    #pragma unroll
    for (int e = 0; e < 8; ++e) se += __expf(acc[e] - mx);
    const float gate_val = 1.0f / se;
    const float l0 = acc[8] + cb[0], l1 = acc[9] + cb[1];
    const float cmx = fmaxf(l0, l1);
    const float e0 = __expf(l0 - cmx), e1 = __expf(l1 - cmx);
    const float inv = 1.0f / (e0 + e1);
    const int pos = atomicAdd(&counts[best], 1);
    bucket[best * TOK + pos] = t;
    gs[t] = gate_val * e0 * inv;
    c1o[t] = e1 * inv;
  }
}

// ---------------- Generic bf16 MFMA GEMM, 128x128 tile, BK=64, optional split-K ----------------
// A: [M,K] bf16 (optionally row-gathered), B: [K,N] fp32 staged coalesced via
// global_load_lds with rotation swizzle n' = (n&~31)|((n+8*((k>>3)&3))&31).
// EPI: 0=store bf16, 1=GELU->bf16, 2=resid fp32 atomic, 3=moe scale atomic, 4=final atomic
struct GemmP {
  const short* A; const float* B; const float* bias;
  float* outf; short* outh;
  const float* resid; const float* aux; const float* sA; const float* sB;
  const int* bucket; const int* counts;
  int N, K, ktc;  // ktc = K-tiles (of 64) per split
};

template<int EPI, bool GATHER>
__global__ __launch_bounds__(256, 3)
void gemm_k(GemmP p)
{
  __shared__ short Al[8192];  // [koctet8][row128][8] linear, 16KB
  __shared__ float Bl[8192];  // [k64][n'128] rotation-swizzled, 32KB
  const int tid = threadIdx.x;
  const int l = tid & 63, w = tid >> 6;
  const int wr = w >> 1, wc = w & 1;
  const int mt = blockIdx.x >> 16 ? 0 : blockIdx.x / (p.N >> 7);
  const int nt = blockIdx.x % (p.N >> 7);
  const int z = blockIdx.z;
  const bool first = (z == 0);
  const int K = p.K, N = p.N;

  int cnt = TOK;
  const short* Abase = p.A;
  const float* Bbase = p.B;
  const float* bias = p.bias;
  const int* bucket = nullptr;
  if (GATHER) {
    const int e = blockIdx.y;
    cnt = p.counts[e];
    if (mt * 128 >= cnt) return;
    bucket = p.bucket + e * TOK;
    Bbase = p.B + (size_t)e * K * N;
    bias = p.bias + (size_t)e * N;
  }

  const short* aptr[4];
  #pragma unroll
  for (int i = 0; i < 4; ++i) {
    const int s = i * 256 + tid;
    const int c = s >> 7, r = s & 127;
    int row;
    if (GATHER) {
      const int bidx = mt * 128 + r;
      row = bucket[bidx < cnt ? bidx : mt * 128];
    } else row = mt * 128 + r;
    aptr[i] = Abase + (size_t)row * K + c * 8;
  }

  // B staging source precompute (per-thread constants)
  const int bk = (tid >> 5) * 2 + (l >> 5) - (w * 2);  // note: recomputed per issue below
  (void)bk;

  f32x4 acc[4][4] = {};
  const int kt0 = z * p.ktc, kt1 = kt0 + p.ktc;
  for (int kt = kt0; kt < kt1; ++kt) {
    #pragma unroll
    for (int i = 0; i < 4; ++i)
      gload_lds16(aptr[i] + kt * 64, (char*)Al + (i * 256 + (tid & 192)) * 16);
    {
      const float* Brow = Bbase + (size_t)(kt * 64) * N + nt * 128;
      #pragma unroll
      for (int i = 0; i < 8; ++i) {
        const int seg = i * 4 + w;               // 0..31, per-wave uniform
        const int k = seg * 2 + (l >> 5);        // row 0..63
        const int q = (k >> 3) & 3;
        const int np = (l & 31) * 4;             // n' (4-aligned)
        const int nsrc = (np & ~31) | ((np + 32 - 8 * q) & 31);
        gload_lds16(Brow + (size_t)k * N + nsrc, (char*)Bl + seg * 1024);
      }
    }
    __syncthreads();
    #pragma unroll
    for (int ks = 0; ks < 2; ++ks) {
      s16x8 af[4], bfr[4];
      #pragma unroll
      for (int mf = 0; mf < 4; ++mf)
        af[mf] = *(const s16x8*)((char*)Al +
            ((ks * 4 + (l >> 4)) * 128 + wr * 64 + mf * 16 + (l & 15)) * 16);
      #pragma unroll
      for (int nf = 0; nf < 4; ++nf) {
        const int col = wc * 64 + nf * 16 + (l & 15);
        const int q = (l >> 4) & 3;
        const int npr = (col & ~31) | ((col + 8 * q) & 31);
        #pragma unroll
        for (int j = 0; j < 8; ++j) {
          const int k = ks * 32 + (l >> 4) * 8 + j;
          bfr[nf][j] = f2bf(Bl[k * 128 + npr]);
        }
      }
      #pragma unroll
      for (int mf = 0; mf < 4; ++mf)
        #pragma unroll
        for (int nf = 0; nf < 4; ++nf)
          acc[mf][nf] = __builtin_amdgcn_mfma_f32_16x16x32_bf16(af[mf], bfr[nf], acc[mf][nf], 0, 0, 0);
    }
    __syncthreads();
  }

  #pragma unroll
  for (int mf = 0; mf < 4; ++mf) {
    #pragma unroll
    for (int i = 0; i < 4; ++i) {
      const int rloc = wr * 64 + mf * 16 + (l >> 4) * 4 + i;
      int grow; bool valid = true;
      if (GATHER) {
        const int bidx = mt * 128 + rloc;
        valid = bidx < cnt;
        grow = valid ? bucket[bidx] : 0;
      } else grow = mt * 128 + rloc;
      float srow = 0.f;
      if (EPI == 3) srow = valid ? p.sA[grow] : 0.f;
      if (EPI == 4) srow = p.sB[grow];
      #pragma unroll
      for (int nf = 0; nf < 4; ++nf) {
        const int col = nt * 128 + wc * 64 + nf * 16 + (l & 15);
        const size_t off = (size_t)grow * N + col;
        const float bc = first ? bias[col] : 0.f;
        if (EPI == 0) {
          if (valid) p.outh[off] = f2bf(acc[mf][nf][i] + bc);
        } else if (EPI == 1) {
          const float v = acc[mf][nf][i] + bc;
          const float gv = 0.5f * v * (1.0f + erff(v * 0.70710678f));
          if (valid) p.outh[off] = f2bf(gv);
        } else if (EPI == 2) {
          atomicAdd(&p.outf[off], acc[mf][nf][i] + bc + (first ? p.resid[off] : 0.f));
        } else if (EPI == 3) {
          if (valid) atomicAdd(&p.outf[off], (acc[mf][nf][i] + bc) * srow);
        } else if (EPI == 4) {
          atomicAdd(&p.outf[off], (acc[mf][nf][i] + bc) * srow +
                    (first ? p.resid[off] + p.aux[off] : 0.f));
        }
      }
    }
  }
}

// ---------------- Flash attention: 4 waves x 16 q-rows, KV tiles of 64 ----------------
__global__ __launch_bounds__(256, 2)
void attn_k(const short* __restrict__ qkv, short* __restrict__ ctx)
{
  __shared__ short Klds[64 * 64];
  __shared__ short Vlds[64 * 64];
  __shared__ short Plds[4 * 16 * 64];
  const int tid = threadIdx.x, l = tid & 63, w = tid >> 6;
  const int qt = blockIdx.x;
  const int bh = blockIdx.y;
  const int b = bh >> 4, h = bh & 15;
  const size_t tbase = (size_t)b * 1024;

  const int sq = qt * 64 + w * 16 + (l & 15);
  s16x8 qf[2];
  #pragma unroll
  for (int ks = 0; ks < 2; ++ks)
    qf[ks] = *(const s16x8*)(qkv + (tbase + sq) * 3072 + h * 64 + ks * 32 + (l >> 4) * 8);

  f32x4 o[4] = {};
  float mrow[4], lrow[4];
  #pragma unroll
  for (int i = 0; i < 4; ++i) { mrow[i] = -1e30f; lrow[i] = 0.f; }

  for (int kt = 0; kt < 16; ++kt) {
    #pragma unroll
    for (int i = 0; i < 2; ++i) {
      const int s = i * 256 + tid;
      const int r = s >> 3, c = s & 7, csrc = c ^ (r & 7);
      const short* gsrc = qkv + (tbase + kt * 64 + r) * 3072 + 1024 + h * 64 + csrc * 8;
      gload_lds16(gsrc, (char*)Klds + (i * 256 + (tid & 192)) * 16);
    }
    #pragma unroll
    for (int i = 0; i < 2; ++i) {
      const int kv0 = (i * 4 + w) * 8;
      s16x8 vv;
      #pragma unroll
      for (int j = 0; j < 8; ++j)
        vv[j] = qkv[(tbase + kt * 64 + kv0 + j) * 3072 + 2048 + h * 64 + l];
      *(s16x8*)((char*)Vlds + ((l * 128 + kv0 * 2) ^ ((l & 7) << 4))) = vv;
    }
    __syncthreads();

    f32x4 sv[4];
    #pragma unroll
    for (int nf = 0; nf < 4; ++nf) {
      f32x4 a = {0.f, 0.f, 0.f, 0.f};
      const int kv = nf * 16 + (l & 15);
      #pragma unroll
      for (int ks = 0; ks < 2; ++ks) {
        const s16x8 kb = *(const s16x8*)((char*)Klds +
            ((kv * 128 + (ks * 32 + (l >> 4) * 8) * 2) ^ ((kv & 7) << 4)));
        a = __builtin_amdgcn_mfma_f32_16x16x32_bf16(qf[ks], kb, a, 0, 0, 0);
      }
      sv[nf] = a * 0.125f;
    }
    float sc[4], ps[4];
    #pragma unroll
    for (int i = 0; i < 4; ++i) {
      float m = fmaxf(fmaxf(sv[0][i], sv[1][i]), fmaxf(sv[2][i], sv[3][i]));
      #pragma unroll
      for (int msk = 1; msk < 16; msk <<= 1) m = fmaxf(m, __shfl_xor(m, msk));
      const float mn = fmaxf(mrow[i], m);
      sc[i] = __expf(mrow[i] - mn);
      mrow[i] = mn;
      ps[i] = 0.f;
    }
    #pragma unroll
    for (int nf = 0; nf < 4; ++nf)
      #pragma unroll
      for (int i = 0; i < 4; ++i) {
        const float pp = __expf(sv[nf][i] - mrow[i]);
        sv[nf][i] = pp;
        ps[i] += pp;
      }
    #pragma unroll
    for (int i = 0; i < 4; ++i) {
      #pragma unroll
      for (int msk = 1; msk < 16; msk <<= 1) ps[i] += __shfl_xor(ps[i], msk);
      lrow[i] = lrow[i] * sc[i] + ps[i];
    }
    #pragma unroll
    for (int nf = 0; nf < 4; ++nf)
      #pragma unroll
      for (int i = 0; i < 4; ++i) o[nf][i] *= sc[i];

    char* pw = (char*)Plds + w * 2048;
    #pragma unroll
    for (int nf = 0; nf < 4; ++nf)
      #pragma unroll
      for (int i = 0; i < 4; ++i) {
        const int q = (l >> 4) * 4 + i;
        *(short*)(pw + ((q * 128 + (nf * 16 + (l & 15)) * 2) ^ ((q & 7) << 4))) = f2bf(sv[nf][i]);
      }
    __syncthreads();
    #pragma unroll
    for (int ks = 0; ks < 2; ++ks) {
      const s16x8 pa = *(const s16x8*)(pw +
          (((l & 15) * 128 + (ks * 32 + (l >> 4) * 8) * 2) ^ ((l & 7) << 4)));
      #pragma unroll
      for (int nf = 0; nf < 4; ++nf) {
        const int dh = nf * 16 + (l & 15);
        const s16x8 vb = *(const s16x8*)((char*)Vlds +
            ((dh * 128 + (ks * 32 + (l >> 4) * 8) * 2) ^ ((dh & 7) << 4)));
        o[nf] = __builtin_amdgcn_mfma_f32_16x16x32_bf16(pa, vb, o[nf], 0, 0, 0);
      }
    }
    __syncthreads();
  }
  #pragma unroll
  for (int i = 0; i < 4; ++i) {
    const float inv = 1.0f / lrow[i];
    const size_t t = tbase + qt * 64 + w * 16 + (l >> 4) * 4 + i;
    #pragma unroll
    for (int nf = 0; nf < 4; ++nf)
      ctx[t * 1024 + h * 64 + nf * 16 + (l & 15)] = f2bf(o[nf][i] * inv);
  }
}

extern "C" void kernel_launch(void* const* d_in, const int* in_sizes, int n_in,
                              void* d_out, int out_size, void* d_ws, size_t ws_size,
                              hipStream_t stream)
{
  const float* x    = (const float*)d_in[0];
  const float* ln1g = (const float*)d_in[1];
  const float* ln1b = (const float*)d_in[2];
  const float* Wqkv = (const float*)d_in[3];
  const float* bqkv = (const float*)d_in[4];
  const float* Wo   = (const float*)d_in[5];
  const float* bo   = (const float*)d_in[6];
  const float* ln2g = (const float*)d_in[7];
  const float* ln2b = (const float*)d_in[8];
  const float* gw   = (const float*)d_in[9];
  const float* W1   = (const float*)d_in[10];
  const float* b1   = (const float*)d_in[11];
  const float* W2   = (const float*)d_in[12];
  const float* b2   = (const float*)d_in[13];
  const float* rW1  = (const float*)d_in[14];
  const float* rb1  = (const float*)d_in[15];
  const float* rW2  = (const float*)d_in[16];
  const float* rb2  = (const float*)d_in[17];
  const float* cw   = (const float*)d_in[18];
  const float* cb   = (const float*)d_in[19];
  float* out = (float*)d_out;

  char* ws = (char*)d_ws;
  const size_t MB = 1024 * 1024;
  short* xn1    = (short*)(ws + 0);          // 4 MB
  short* qkv    = (short*)(ws + 4 * MB);     // 12 MB
  short* he     = (short*)(ws + 4 * MB);     // 16 MB (aliases qkv+ctx, dead by then)
  short* ctx    = (short*)(ws + 16 * MB);    // 4 MB
  float* x1     = (float*)(ws + 20 * MB);    // 8 MB
  short* xn2    = (short*)(ws + 28 * MB);    // 4 MB
  short* hr     = (short*)(ws + 32 * MB);    // 16 MB
  float* moe    = (float*)(ws + 48 * MB);    // 8 MB
  int*   counts = (int*)(ws + 56 * MB);
  int*   bucket = (int*)(ws + 56 * MB + 256);
  float* gs     = (float*)(ws + 56 * MB + 256 + 64 * 1024);
  float* c1     = (float*)(ws + 56 * MB + 256 + 64 * 1024 + 8192);

  hipMemsetAsync(counts, 0, 8 * sizeof(int), stream);
  hipMemsetAsync(x1, 0, TOK * NDIM * sizeof(float), stream);
  hipMemsetAsync(moe, 0, TOK * NDIM * sizeof(float), stream);
  hipMemsetAsync(out, 0, TOK * NDIM * sizeof(float), stream);

  ln_k<<<TOK, 256, 0, stream>>>(x, ln1g, ln1b, xn1);

  GemmP p{};
  p.A = xn1; p.B = Wqkv; p.bias = bqkv; p.outh = qkv; p.N = 3072; p.K = 1024; p.ktc = 16;
  gemm_k<0, false><<<dim3(16 * 24), 256, 0, stream>>>(p);

  attn_k<<<dim3(16, 32), 256, 0, stream>>>(qkv, ctx);

  // x1 = x + ctx @ Wo + bo  (split-K = 2)
  p = GemmP{};
  p.A = ctx; p.B = Wo; p.bias = bo; p.outf = x1; p.resid = x; p.N = 1024; p.K = 1024; p.ktc = 8;
  gemm_k<2, false><<<dim3(16 * 8, 1, 2), 256, 0, stream>>>(p);

  ln_k<<<TOK, 256, 0, stream>>>(x1, ln2g, ln2b, xn2);
  gate_k<<<TOK / 4, 256, 0, stream>>>(x1, ln2g, ln2b, gw, cw, cb, counts, bucket, gs, c1);

  // he = gelu(gather(xn2) @ W1 + b1)  (no split: nonlinear epilogue)
  p = GemmP{};
  p.A = xn2; p.B = W1; p.bias = b1; p.outh = he; p.N = 4096; p.K = 1024; p.ktc = 16;
  p.bucket = bucket; p.counts = counts;
  gemm_k<1, true><<<dim3(16 * 32, 8), 256, 0, stream>>>(p);

  // moe = (he @ W2 + b2) * gs  (split-K = 4)
  p = GemmP{};
  p.A = he; p.B = W2; p.bias = b2; p.outf = moe; p.sA = gs; p.N = 1024; p.K = 4096; p.ktc = 16;
  p.bucket = bucket; p.counts = counts;
  gemm_k<3, true><<<dim3(16 * 8, 8, 4), 256, 0, stream>>>(p);

  // hr = gelu(xn2 @ rW1 + rb1)  (no split)
  p = GemmP{};
  p.A = xn2; p.B = rW1; p.bias = rb1; p.outh = hr; p.N = 4096; p.K = 1024; p.ktc = 16;
  gemm_k<1, false><<<dim3(16 * 32), 256, 0, stream>>>(p);

  // out = x1 + moe + (hr @ rW2 + rb2) * c1  (split-K = 4)
  p = GemmP{};
  p.A = hr; p.B = rW2; p.bias = rb2; p.outf = out; p.resid = x1; p.aux = moe; p.sB = c1;
  p.N = 1024; p.K = 4096; p.ktc = 16;
  gemm_k<4, false><<<dim3(16 * 8, 1, 4), 256, 0, stream>>>(p);
}

// Round 3
// 579.362 us; speedup vs baseline: 1.2651x; 1.0332x over previous
//
#include <hip/hip_runtime.h>
#include <math.h>

#define TOK 2048
#define NDIM 1024

typedef __attribute__((ext_vector_type(4))) float f32x4;
typedef __attribute__((ext_vector_type(8))) short s16x8;
typedef __attribute__((ext_vector_type(4))) short s16x4;

__device__ __forceinline__ short f2bf(float x) {
  unsigned int u = __builtin_bit_cast(unsigned int, x);
  unsigned int r = (u + 0x7fffu + ((u >> 16) & 1u)) >> 16;
  return (short)r;
}
__device__ __forceinline__ void gload_lds16(const void* g, void* l) {
  __builtin_amdgcn_global_load_lds((const __attribute__((address_space(1))) void*)g,
                                   (__attribute__((address_space(3))) void*)l, 16, 0, 0);
}

// ---------------- LayerNorm: fp32 in -> bf16 out ----------------
__global__ __launch_bounds__(256)
void ln_k(const float* __restrict__ x, const float* __restrict__ g,
          const float* __restrict__ bb, short* __restrict__ out)
{
  const int row = blockIdx.x, tid = threadIdx.x;
  const f32x4 xv = *(const f32x4*)(x + (size_t)row * NDIM + tid * 4);
  float s = xv[0] + xv[1] + xv[2] + xv[3];
  float s2 = xv[0]*xv[0] + xv[1]*xv[1] + xv[2]*xv[2] + xv[3]*xv[3];
  #pragma unroll
  for (int m = 1; m < 64; m <<= 1) { s += __shfl_xor(s, m); s2 += __shfl_xor(s2, m); }
  __shared__ float red[8];
  const int w = tid >> 6, l = tid & 63;
  if (l == 0) { red[w] = s; red[4 + w] = s2; }
  __syncthreads();
  s = red[0] + red[1] + red[2] + red[3];
  s2 = red[4] + red[5] + red[6] + red[7];
  const float mean = s * (1.0f / NDIM);
  const float var = s2 * (1.0f / NDIM) - mean * mean;
  const float rstd = rsqrtf(var + 1e-5f);
  const f32x4 gv = *(const f32x4*)(g + tid * 4);
  const f32x4 bv = *(const f32x4*)(bb + tid * 4);
  s16x4 ov;
  #pragma unroll
  for (int j = 0; j < 4; ++j) ov[j] = f2bf((xv[j] - mean) * rstd * gv[j] + bv[j]);
  *(s16x4*)(out + (size_t)row * NDIM + tid * 4) = ov;
}

// ---------------- Gate: fp32 LN recompute + gate/coef softmax + buckets ----------------
__global__ __launch_bounds__(256)
void gate_k(const float* __restrict__ x1, const float* __restrict__ g,
            const float* __restrict__ bb, const float* __restrict__ gw,
            const float* __restrict__ cw, const float* __restrict__ cb,
            int* __restrict__ counts, int* __restrict__ bucket,
            float* __restrict__ gs, float* __restrict__ c1o)
{
  const int tid = threadIdx.x, l = tid & 63, w = tid >> 6;
  const int t = blockIdx.x * 4 + w;
  f32x4 xv[4];
  #pragma unroll
  for (int it = 0; it < 4; ++it)
    xv[it] = *(const f32x4*)(x1 + (size_t)t * NDIM + it * 256 + l * 4);
  float s = 0.f, s2 = 0.f;
  #pragma unroll
  for (int it = 0; it < 4; ++it)
    #pragma unroll
    for (int j = 0; j < 4; ++j) { s += xv[it][j]; s2 += xv[it][j] * xv[it][j]; }
  #pragma unroll
  for (int m = 1; m < 64; m <<= 1) { s += __shfl_xor(s, m); s2 += __shfl_xor(s2, m); }
  const float mean = s * (1.0f / NDIM);
  const float rstd = rsqrtf(s2 * (1.0f / NDIM) - mean * mean + 1e-5f);
  float acc[10];
  #pragma unroll
  for (int j = 0; j < 10; ++j) acc[j] = 0.f;
  #pragma unroll
  for (int it = 0; it < 4; ++it) {
    #pragma unroll
    for (int j = 0; j < 4; ++j) {
      const int d0 = it * 256 + l * 4 + j;
      const float xn = (xv[it][j] - mean) * rstd * g[d0] + bb[d0];
      const f32x4 g0 = *(const f32x4*)(gw + (size_t)d0 * 8);
      const f32x4 g1 = *(const f32x4*)(gw + (size_t)d0 * 8 + 4);
      #pragma unroll
      for (int q = 0; q < 4; ++q) { acc[q] += xn * g0[q]; acc[4 + q] += xn * g1[q]; }
      acc[8] += xn * cw[d0 * 2]; acc[9] += xn * cw[d0 * 2 + 1];
    }
  }
  #pragma unroll
  for (int j = 0; j < 10; ++j)
    #pragma unroll
    for (int m = 1; m < 64; m <<= 1) acc[j] += __shfl_xor(acc[j], m);
  if (l == 0) {
    int best = 0; float mx = acc[0];
    #pragma unroll
    for (int e = 1; e < 8; ++e) if (acc[e] > mx) { mx = acc[e]; best = e; }
    float se = 0.f;
    #pragma unroll
    for (int e = 0; e < 8; ++e) se += __expf(acc[e] - mx);
    const float gate_val = 1.0f / se;
    const float l0 = acc[8] + cb[0], l1 = acc[9] + cb[1];
    const float cmx = fmaxf(l0, l1);
    const float e0 = __expf(l0 - cmx), e1 = __expf(l1 - cmx);
    const float inv = 1.0f / (e0 + e1);
    const int pos = atomicAdd(&counts[best], 1);
    bucket[best * TOK + pos] = t;
    gs[t] = gate_val * e0 * inv;
    c1o[t] = e1 * inv;
  }
}

// ---------------- bf16 MFMA GEMM, 128x64 tile, BK=64, 2-phase pipeline ----------------
// A: [M,K] bf16 (optionally row-gathered), B: [K,N] fp32 staged linear [k64][n64].
// EPI: 0=store bf16, 1=GELU->bf16, 2=resid fp32 atomic, 3=moe scale atomic, 4=final atomic
struct GemmP {
  const short* A; const float* B; const float* bias;
  float* outf; short* outh;
  const float* resid; const float* aux; const float* sA; const float* sB;
  const int* bucket; const int* counts;
  int N, K, ktc;  // ktc = K-tiles (of 64) per split
};

template<int EPI, bool GATHER>
__global__ __launch_bounds__(256, 2)
void gemm_k(GemmP p)
{
  __shared__ short Al[2][8192];  // [koctet8][row128][8] linear, 16KB each
  __shared__ float Bl[2][4096];  // [k64][n64] linear, 16KB each
  const int tid = threadIdx.x;
  const int l = tid & 63, w = tid >> 6;
  const int wr = w >> 1, wc = w & 1;
  const int ntn = p.N >> 6;
  const int mt = blockIdx.x / ntn;
  const int nt = blockIdx.x % ntn;
  const int z = blockIdx.z;
  const bool first = (z == 0);
  const int K = p.K, N = p.N;

  int cnt = TOK;
  const short* Abase = p.A;
  const float* Bbase = p.B;
  const float* bias = p.bias;
  const int* bucket = nullptr;
  if (GATHER) {
    const int e = blockIdx.y;
    cnt = p.counts[e];
    if (mt * 128 >= cnt) return;
    bucket = p.bucket + e * TOK;
    Bbase = p.B + (size_t)e * K * N;
    bias = p.bias + (size_t)e * N;
  }

  // A staging source pointers (4 x 16B per thread per K-tile)
  const short* aptr[4];
  #pragma unroll
  for (int i = 0; i < 4; ++i) {
    const int s = i * 256 + tid;
    const int c = s >> 7, r = s & 127;
    int row;
    if (GATHER) {
      const int bidx = mt * 128 + r;
      row = bucket[bidx < cnt ? bidx : mt * 128];
    } else row = mt * 128 + r;
    aptr[i] = Abase + (size_t)row * K + c * 8;
  }
  // B staging source offset (4 x 16B per thread per K-tile)
  const float* Bcol = Bbase + nt * 64;

  const int kt0 = z * p.ktc, kt1 = kt0 + p.ktc;

  auto stage = [&](int kt, int buf) {
    #pragma unroll
    for (int i = 0; i < 4; ++i)
      gload_lds16(aptr[i] + kt * 64, (char*)Al[buf] + (i * 256 + (tid & 192)) * 16);
    const float* Brow = Bcol + (size_t)(kt * 64) * N;
    #pragma unroll
    for (int i = 0; i < 4; ++i) {
      const int seg = i * 4 + w;  // 0..15, wave-uniform
      gload_lds16(Brow + (size_t)(seg * 4 + (l >> 4)) * N + (l & 15) * 4,
                  (char*)Bl[buf] + seg * 1024);
    }
  };

  f32x4 acc[4][2] = {};
  stage(kt0, 0);
  __syncthreads();
  for (int kt = kt0; kt < kt1; ++kt) {
    const int cur = (kt - kt0) & 1;
    if (kt + 1 < kt1) stage(kt + 1, cur ^ 1);
    #pragma unroll
    for (int ks = 0; ks < 2; ++ks) {
      s16x8 af[4], bfr[2];
      #pragma unroll
      for (int mf = 0; mf < 4; ++mf)
        af[mf] = *(const s16x8*)((char*)Al[cur] +
            ((ks * 4 + (l >> 4)) * 128 + wr * 64 + mf * 16 + (l & 15)) * 16);
      #pragma unroll
      for (int nf = 0; nf < 2; ++nf) {
        const int col = wc * 32 + nf * 16 + (l & 15);
        #pragma unroll
        for (int j = 0; j < 8; ++j) {
          const int k = ks * 32 + (l >> 4) * 8 + j;
          bfr[nf][j] = f2bf(Bl[cur][k * 64 + col]);
        }
      }
      #pragma unroll
      for (int mf = 0; mf < 4; ++mf)
        #pragma unroll
        for (int nf = 0; nf < 2; ++nf)
          acc[mf][nf] = __builtin_amdgcn_mfma_f32_16x16x32_bf16(af[mf], bfr[nf], acc[mf][nf], 0, 0, 0);
    }
    __syncthreads();
  }

  #pragma unroll
  for (int mf = 0; mf < 4; ++mf) {
    #pragma unroll
    for (int i = 0; i < 4; ++i) {
      const int rloc = wr * 64 + mf * 16 + (l >> 4) * 4 + i;
      int grow; bool valid = true;
      if (GATHER) {
        const int bidx = mt * 128 + rloc;
        valid = bidx < cnt;
        grow = valid ? bucket[bidx] : 0;
      } else grow = mt * 128 + rloc;
      float srow = 0.f;
      if (EPI == 3) srow = valid ? p.sA[grow] : 0.f;
      if (EPI == 4) srow = p.sB[grow];
      #pragma unroll
      for (int nf = 0; nf < 2; ++nf) {
        const int col = nt * 64 + wc * 32 + nf * 16 + (l & 15);
        const size_t off = (size_t)grow * N + col;
        const float bc = first ? bias[col] : 0.f;
        if (EPI == 0) {
          if (valid) p.outh[off] = f2bf(acc[mf][nf][i] + bc);
        } else if (EPI == 1) {
          const float v = acc[mf][nf][i] + bc;
          const float gv = 0.5f * v * (1.0f + erff(v * 0.70710678f));
          if (valid) p.outh[off] = f2bf(gv);
        } else if (EPI == 2) {
          atomicAdd(&p.outf[off], acc[mf][nf][i] + bc + (first ? p.resid[off] : 0.f));
        } else if (EPI == 3) {
          if (valid) atomicAdd(&p.outf[off], (acc[mf][nf][i] + bc) * srow);
        } else if (EPI == 4) {
          atomicAdd(&p.outf[off], (acc[mf][nf][i] + bc) * srow +
                    (first ? p.resid[off] + p.aux[off] : 0.f));
        }
      }
    }
  }
}

// ---------------- Flash attention: 4 waves x 16 q-rows, KV tiles of 64 ----------------
__global__ __launch_bounds__(256, 2)
void attn_k(const short* __restrict__ qkv, short* __restrict__ ctx)
{
  __shared__ short Klds[64 * 64];
  __shared__ short Vlds[64 * 64];
  __shared__ short Plds[4 * 16 * 64];
  const int tid = threadIdx.x, l = tid & 63, w = tid >> 6;
  const int qt = blockIdx.x;
  const int bh = blockIdx.y;
  const int b = bh >> 4, h = bh & 15;
  const size_t tbase = (size_t)b * 1024;

  const int sq = qt * 64 + w * 16 + (l & 15);
  s16x8 qf[2];
  #pragma unroll
  for (int ks = 0; ks < 2; ++ks)
    qf[ks] = *(const s16x8*)(qkv + (tbase + sq) * 3072 + h * 64 + ks * 32 + (l >> 4) * 8);

  f32x4 o[4] = {};
  float mrow[4], lrow[4];
  #pragma unroll
  for (int i = 0; i < 4; ++i) { mrow[i] = -1e30f; lrow[i] = 0.f; }

  for (int kt = 0; kt < 16; ++kt) {
    #pragma unroll
    for (int i = 0; i < 2; ++i) {
      const int s = i * 256 + tid;
      const int r = s >> 3, c = s & 7, csrc = c ^ (r & 7);
      const short* gsrc = qkv + (tbase + kt * 64 + r) * 3072 + 1024 + h * 64 + csrc * 8;
      gload_lds16(gsrc, (char*)Klds + (i * 256 + (tid & 192)) * 16);
    }
    #pragma unroll
    for (int i = 0; i < 2; ++i) {
      const int kv0 = (i * 4 + w) * 8;
      s16x8 vv;
      #pragma unroll
      for (int j = 0; j < 8; ++j)
        vv[j] = qkv[(tbase + kt * 64 + kv0 + j) * 3072 + 2048 + h * 64 + l];
      *(s16x8*)((char*)Vlds + ((l * 128 + kv0 * 2) ^ ((l & 7) << 4))) = vv;
    }
    __syncthreads();

    f32x4 sv[4];
    #pragma unroll
    for (int nf = 0; nf < 4; ++nf) {
      f32x4 a = {0.f, 0.f, 0.f, 0.f};
      const int kv = nf * 16 + (l & 15);
      #pragma unroll
      for (int ks = 0; ks < 2; ++ks) {
        const s16x8 kb = *(const s16x8*)((char*)Klds +
            ((kv * 128 + (ks * 32 + (l >> 4) * 8) * 2) ^ ((kv & 7) << 4)));
        a = __builtin_amdgcn_mfma_f32_16x16x32_bf16(qf[ks], kb, a, 0, 0, 0);
      }
      sv[nf] = a * 0.125f;
    }
    float sc[4], ps[4];
    #pragma unroll
    for (int i = 0; i < 4; ++i) {
      float m = fmaxf(fmaxf(sv[0][i], sv[1][i]), fmaxf(sv[2][i], sv[3][i]));
      #pragma unroll
      for (int msk = 1; msk < 16; msk <<= 1) m = fmaxf(m, __shfl_xor(m, msk));
      const float mn = fmaxf(mrow[i], m);
      sc[i] = __expf(mrow[i] - mn);
      mrow[i] = mn;
      ps[i] = 0.f;
    }
    #pragma unroll
    for (int nf = 0; nf < 4; ++nf)
      #pragma unroll
      for (int i = 0; i < 4; ++i) {
        const float pp = __expf(sv[nf][i] - mrow[i]);
        sv[nf][i] = pp;
        ps[i] += pp;
      }
    #pragma unroll
    for (int i = 0; i < 4; ++i) {
      #pragma unroll
      for (int msk = 1; msk < 16; msk <<= 1) ps[i] += __shfl_xor(ps[i], msk);
      lrow[i] = lrow[i] * sc[i] + ps[i];
    }
    #pragma unroll
    for (int nf = 0; nf < 4; ++nf)
      #pragma unroll
      for (int i = 0; i < 4; ++i) o[nf][i] *= sc[i];

    char* pw = (char*)Plds + w * 2048;
    #pragma unroll
    for (int nf = 0; nf < 4; ++nf)
      #pragma unroll
      for (int i = 0; i < 4; ++i) {
        const int q = (l >> 4) * 4 + i;
        *(short*)(pw + ((q * 128 + (nf * 16 + (l & 15)) * 2) ^ ((q & 7) << 4))) = f2bf(sv[nf][i]);
      }
    __syncthreads();
    #pragma unroll
    for (int ks = 0; ks < 2; ++ks) {
      const s16x8 pa = *(const s16x8*)(pw +
          (((l & 15) * 128 + (ks * 32 + (l >> 4) * 8) * 2) ^ ((l & 7) << 4)));
      #pragma unroll
      for (int nf = 0; nf < 4; ++nf) {
        const int dh = nf * 16 + (l & 15);
        const s16x8 vb = *(const s16x8*)((char*)Vlds +
            ((dh * 128 + (ks * 32 + (l >> 4) * 8) * 2) ^ ((dh & 7) << 4)));
        o[nf] = __builtin_amdgcn_mfma_f32_16x16x32_bf16(pa, vb, o[nf], 0, 0, 0);
      }
    }
    __syncthreads();
  }
  #pragma unroll
  for (int i = 0; i < 4; ++i) {
    const float inv = 1.0f / lrow[i];
    const size_t t = tbase + qt * 64 + w * 16 + (l >> 4) * 4 + i;
    #pragma unroll
    for (int nf = 0; nf < 4; ++nf)
      ctx[t * 1024 + h * 64 + nf * 16 + (l & 15)] = f2bf(o[nf][i] * inv);
  }
}

extern "C" void kernel_launch(void* const* d_in, const int* in_sizes, int n_in,
                              void* d_out, int out_size, void* d_ws, size_t ws_size,
                              hipStream_t stream)
{
  const float* x    = (const float*)d_in[0];
  const float* ln1g = (const float*)d_in[1];
  const float* ln1b = (const float*)d_in[2];
  const float* Wqkv = (const float*)d_in[3];
  const float* bqkv = (const float*)d_in[4];
  const float* Wo   = (const float*)d_in[5];
  const float* bo   = (const float*)d_in[6];
  const float* ln2g = (const float*)d_in[7];
  const float* ln2b = (const float*)d_in[8];
  const float* gw   = (const float*)d_in[9];
  const float* W1   = (const float*)d_in[10];
  const float* b1   = (const float*)d_in[11];
  const float* W2   = (const float*)d_in[12];
  const float* b2   = (const float*)d_in[13];
  const float* rW1  = (const float*)d_in[14];
  const float* rb1  = (const float*)d_in[15];
  const float* rW2  = (const float*)d_in[16];
  const float* rb2  = (const float*)d_in[17];
  const float* cw   = (const float*)d_in[18];
  const float* cb   = (const float*)d_in[19];
  float* out = (float*)d_out;

  char* ws = (char*)d_ws;
  const size_t MB = 1024 * 1024;
  short* xn1    = (short*)(ws + 0);          // 4 MB
  short* qkv    = (short*)(ws + 4 * MB);     // 12 MB
  short* he     = (short*)(ws + 4 * MB);     // 16 MB (aliases qkv+ctx, dead by then)
  short* ctx    = (short*)(ws + 16 * MB);    // 4 MB
  float* x1     = (float*)(ws + 20 * MB);    // 8 MB
  short* xn2    = (short*)(ws + 28 * MB);    // 4 MB
  short* hr     = (short*)(ws + 32 * MB);    // 16 MB
  float* moe    = (float*)(ws + 48 * MB);    // 8 MB
  int*   counts = (int*)(ws + 56 * MB);
  int*   bucket = (int*)(ws + 56 * MB + 256);
  float* gs     = (float*)(ws + 56 * MB + 256 + 64 * 1024);
  float* c1     = (float*)(ws + 56 * MB + 256 + 64 * 1024 + 8192);

  hipMemsetAsync(counts, 0, 8 * sizeof(int), stream);
  hipMemsetAsync(x1, 0, TOK * NDIM * sizeof(float), stream);
  hipMemsetAsync(moe, 0, TOK * NDIM * sizeof(float), stream);
  hipMemsetAsync(out, 0, TOK * NDIM * sizeof(float), stream);

  ln_k<<<TOK, 256, 0, stream>>>(x, ln1g, ln1b, xn1);

  GemmP p{};
  p.A = xn1; p.B = Wqkv; p.bias = bqkv; p.outh = qkv; p.N = 3072; p.K = 1024; p.ktc = 16;
  gemm_k<0, false><<<dim3(16 * 48), 256, 0, stream>>>(p);

  attn_k<<<dim3(16, 32), 256, 0, stream>>>(qkv, ctx);

  // x1 = x + ctx @ Wo + bo  (split-K = 2)
  p = GemmP{};
  p.A = ctx; p.B = Wo; p.bias = bo; p.outf = x1; p.resid = x; p.N = 1024; p.K = 1024; p.ktc = 8;
  gemm_k<2, false><<<dim3(16 * 16, 1, 2), 256, 0, stream>>>(p);

  ln_k<<<TOK, 256, 0, stream>>>(x1, ln2g, ln2b, xn2);
  gate_k<<<TOK / 4, 256, 0, stream>>>(x1, ln2g, ln2b, gw, cw, cb, counts, bucket, gs, c1);

  // he = gelu(gather(xn2) @ W1 + b1)
  p = GemmP{};
  p.A = xn2; p.B = W1; p.bias = b1; p.outh = he; p.N = 4096; p.K = 1024; p.ktc = 16;
  p.bucket = bucket; p.counts = counts;
  gemm_k<1, true><<<dim3(16 * 64, 8), 256, 0, stream>>>(p);

  // moe = (he @ W2 + b2) * gs  (split-K = 4)
  p = GemmP{};
  p.A = he; p.B = W2; p.bias = b2; p.outf = moe; p.sA = gs; p.N = 1024; p.K = 4096; p.ktc = 16;
  p.bucket = bucket; p.counts = counts;
  gemm_k<3, true><<<dim3(16 * 16, 8, 4), 256, 0, stream>>>(p);

  // hr = gelu(xn2 @ rW1 + rb1)
  p = GemmP{};
  p.A = xn2; p.B = rW1; p.bias = rb1; p.outh = hr; p.N = 4096; p.K = 1024; p.ktc = 16;
  gemm_k<1, false><<<dim3(16 * 64), 256, 0, stream>>>(p);

  // out = x1 + moe + (hr @ rW2 + rb2) * c1  (split-K = 4)
  p = GemmP{};
  p.A = hr; p.B = rW2; p.bias = rb2; p.outf = out; p.resid = x1; p.aux = moe; p.sB = c1;
  p.N = 1024; p.K = 4096; p.ktc = 16;
  gemm_k<4, false><<<dim3(16 * 16, 1, 4), 256, 0, stream>>>(p);
}

// Round 4
// 511.283 us; speedup vs baseline: 1.4336x; 1.1332x over previous
//
#include <hip/hip_runtime.h>
#include <math.h>

#define TOK 2048
#define NDIM 1024

typedef __attribute__((ext_vector_type(4))) float f32x4;
typedef __attribute__((ext_vector_type(8))) short s16x8;
typedef __attribute__((ext_vector_type(4))) short s16x4;

__device__ __forceinline__ short f2bf(float x) {
  unsigned int u = __builtin_bit_cast(unsigned int, x);
  unsigned int r = (u + 0x7fffu + ((u >> 16) & 1u)) >> 16;
  return (short)r;
}
__device__ __forceinline__ void gload_lds16(const void* g, void* l) {
  __builtin_amdgcn_global_load_lds((const __attribute__((address_space(1))) void*)g,
                                   (__attribute__((address_space(3))) void*)l, 16, 0, 0);
}

// ---------------- Weight pack: [K][N] fp32 -> tiles [nt][kt] of 8KB bf16 ----------------
// Tile inner layout: 16B chunk at byte (col*128 + od*16) holds W[k0+o*8+j][n0+col],
// o = od ^ (col&7)  (XOR pre-swizzle so GEMM ds_read_b128 frags are conflict-free).
struct PackP { const float* src; short* dst; int K, N, nkt; };
__global__ __launch_bounds__(256)
void pack_k(PackP p)
{
  __shared__ float T[64 * 65];
  const int e = blockIdx.y;
  const int nkt = p.nkt;
  const int nt = blockIdx.x / nkt, kt = blockIdx.x % nkt;
  const float* src = p.src + (size_t)e * p.K * p.N + (size_t)(kt * 64) * p.N + nt * 64;
  const int t = threadIdx.x;
  #pragma unroll
  for (int i = 0; i < 16; ++i) {
    const int k = i * 4 + (t >> 6);
    T[k * 65 + (t & 63)] = src[(size_t)k * p.N + (t & 63)];
  }
  __syncthreads();
  short* dst = p.dst + ((size_t)e * gridDim.x + blockIdx.x) * 4096 + t * 16;
  s16x8 v[2];
  #pragma unroll
  for (int j2 = 0; j2 < 2; ++j2) {
    const int chunk = t * 2 + j2;
    const int col = chunk >> 3, od = chunk & 7, o = od ^ (col & 7);
    #pragma unroll
    for (int j = 0; j < 8; ++j) v[j2][j] = f2bf(T[(o * 8 + j) * 65 + col]);
  }
  *(s16x8*)dst = v[0];
  *(s16x8*)(dst + 8) = v[1];
}

// ---------------- LayerNorm: fp32 in -> bf16 out ----------------
__global__ __launch_bounds__(256)
void ln_k(const float* __restrict__ x, const float* __restrict__ g,
          const float* __restrict__ bb, short* __restrict__ out)
{
  const int row = blockIdx.x, tid = threadIdx.x;
  const f32x4 xv = *(const f32x4*)(x + (size_t)row * NDIM + tid * 4);
  float s = xv[0] + xv[1] + xv[2] + xv[3];
  float s2 = xv[0]*xv[0] + xv[1]*xv[1] + xv[2]*xv[2] + xv[3]*xv[3];
  #pragma unroll
  for (int m = 1; m < 64; m <<= 1) { s += __shfl_xor(s, m); s2 += __shfl_xor(s2, m); }
  __shared__ float red[8];
  const int w = tid >> 6, l = tid & 63;
  if (l == 0) { red[w] = s; red[4 + w] = s2; }
  __syncthreads();
  s = red[0] + red[1] + red[2] + red[3];
  s2 = red[4] + red[5] + red[6] + red[7];
  const float mean = s * (1.0f / NDIM);
  const float var = s2 * (1.0f / NDIM) - mean * mean;
  const float rstd = rsqrtf(var + 1e-5f);
  const f32x4 gv = *(const f32x4*)(g + tid * 4);
  const f32x4 bv = *(const f32x4*)(bb + tid * 4);
  s16x4 ov;
  #pragma unroll
  for (int j = 0; j < 4; ++j) ov[j] = f2bf((xv[j] - mean) * rstd * gv[j] + bv[j]);
  *(s16x4*)(out + (size_t)row * NDIM + tid * 4) = ov;
}

// ---------------- Gate: fp32 LN recompute + gate/coef softmax + buckets ----------------
__global__ __launch_bounds__(256)
void gate_k(const float* __restrict__ x1, const float* __restrict__ g,
            const float* __restrict__ bb, const float* __restrict__ gw,
            const float* __restrict__ cw, const float* __restrict__ cb,
            int* __restrict__ counts, int* __restrict__ bucket,
            float* __restrict__ gs, float* __restrict__ c1o)
{
  const int tid = threadIdx.x, l = tid & 63, w = tid >> 6;
  const int t = blockIdx.x * 4 + w;
  f32x4 xv[4];
  #pragma unroll
  for (int it = 0; it < 4; ++it)
    xv[it] = *(const f32x4*)(x1 + (size_t)t * NDIM + it * 256 + l * 4);
  float s = 0.f, s2 = 0.f;
  #pragma unroll
  for (int it = 0; it < 4; ++it)
    #pragma unroll
    for (int j = 0; j < 4; ++j) { s += xv[it][j]; s2 += xv[it][j] * xv[it][j]; }
  #pragma unroll
  for (int m = 1; m < 64; m <<= 1) { s += __shfl_xor(s, m); s2 += __shfl_xor(s2, m); }
  const float mean = s * (1.0f / NDIM);
  const float rstd = rsqrtf(s2 * (1.0f / NDIM) - mean * mean + 1e-5f);
  float acc[10];
  #pragma unroll
  for (int j = 0; j < 10; ++j) acc[j] = 0.f;
  #pragma unroll
  for (int it = 0; it < 4; ++it) {
    #pragma unroll
    for (int j = 0; j < 4; ++j) {
      const int d0 = it * 256 + l * 4 + j;
      const float xn = (xv[it][j] - mean) * rstd * g[d0] + bb[d0];
      const f32x4 g0 = *(const f32x4*)(gw + (size_t)d0 * 8);
      const f32x4 g1 = *(const f32x4*)(gw + (size_t)d0 * 8 + 4);
      #pragma unroll
      for (int q = 0; q < 4; ++q) { acc[q] += xn * g0[q]; acc[4 + q] += xn * g1[q]; }
      acc[8] += xn * cw[d0 * 2]; acc[9] += xn * cw[d0 * 2 + 1];
    }
  }
  #pragma unroll
  for (int j = 0; j < 10; ++j)
    #pragma unroll
    for (int m = 1; m < 64; m <<= 1) acc[j] += __shfl_xor(acc[j], m);
  if (l == 0) {
    int best = 0; float mx = acc[0];
    #pragma unroll
    for (int e = 1; e < 8; ++e) if (acc[e] > mx) { mx = acc[e]; best = e; }
    float se = 0.f;
    #pragma unroll
    for (int e = 0; e < 8; ++e) se += __expf(acc[e] - mx);
    const float gate_val = 1.0f / se;
    const float l0 = acc[8] + cb[0], l1 = acc[9] + cb[1];
    const float cmx = fmaxf(l0, l1);
    const float e0 = __expf(l0 - cmx), e1 = __expf(l1 - cmx);
    const float inv = 1.0f / (e0 + e1);
    const int pos = atomicAdd(&counts[best], 1);
    bucket[best * TOK + pos] = t;
    gs[t] = gate_val * e0 * inv;
    c1o[t] = e1 * inv;
  }
}

// ---------------- bf16 MFMA GEMM, 128x64 tile, BK=64, packed-B, 2-phase ----------------
// A: [M,K] bf16 row-major (optionally row-gathered); staged 8 lanes/row x 128B chunks
//    into LDS [row128][oct^(row&7)][16B].  B: packed tiles (see pack_k), staged linear.
// EPI: 0=store bf16, 1=GELU->bf16, 2=resid fp32 atomic, 3=moe scale atomic, 4=final atomic
struct GemmP {
  const short* A; const short* Bp; const float* bias;
  float* outf; short* outh;
  const float* resid; const float* aux; const float* sA; const float* sB;
  const int* bucket; const int* counts;
  int N, K, ktc;  // ktc = K-tiles (of 64) per split
};

template<int EPI, bool GATHER>
__global__ __launch_bounds__(256, 3)
void gemm_k(GemmP p)
{
  __shared__ short Al[2][8192];  // 16KB each: [row128][octd8][8] xor-swizzled
  __shared__ short Bl[2][4096];  // 8KB each:  [col64][octd8][8] xor-swizzled (as packed)
  const int tid = threadIdx.x;
  const int l = tid & 63, w = tid >> 6;
  const int wr = w >> 1, wc = w & 1;
  const int ntn = p.N >> 6, nkt = p.K >> 6;
  const int mt = blockIdx.x / ntn;
  const int nt = blockIdx.x % ntn;
  const int z = blockIdx.z;
  const bool first = (z == 0);
  const int K = p.K, N = p.N;

  int cnt = TOK;
  const short* Abase = p.A;
  const float* bias = p.bias;
  const int* bucket = nullptr;
  int e = 0;
  if (GATHER) {
    e = blockIdx.y;
    cnt = p.counts[e];
    if (mt * 128 >= cnt) return;
    bucket = p.bucket + e * TOK;
    bias = p.bias + (size_t)e * N;
  }
  const short* btile = p.Bp + ((size_t)(e * ntn + nt) * nkt) * 4096;

  // A staging source pointers: chunk c = i*256+tid; row=c>>3, dest-octet=tid&7,
  // source-octet = (tid&7) ^ (row&7)  (pre-swizzled source, linear LDS dest)
  const short* aptr[4];
  #pragma unroll
  for (int i = 0; i < 4; ++i) {
    const int rl = (i * 256 + tid) >> 3;
    int row;
    if (GATHER) {
      const int bidx = mt * 128 + rl;
      row = bucket[bidx < cnt ? bidx : mt * 128];
    } else row = mt * 128 + rl;
    aptr[i] = Abase + (size_t)row * K + ((tid & 7) ^ (rl & 7)) * 8;
  }

  const int kt0 = z * p.ktc, kt1 = kt0 + p.ktc;

  auto stage = [&](int kt, int buf) {
    const short* bsrc = btile + kt * 4096;
    #pragma unroll
    for (int j = 0; j < 2; ++j)
      gload_lds16(bsrc + (j * 256 + tid) * 8, (char*)Bl[buf] + (j * 256 + (tid & 192)) * 16);
    #pragma unroll
    for (int i = 0; i < 4; ++i)
      gload_lds16(aptr[i] + kt * 64, (char*)Al[buf] + (i * 256 + (tid & 192)) * 16);
  };

  f32x4 acc[4][2] = {};
  stage(kt0, 0);
  __syncthreads();
  for (int kt = kt0; kt < kt1; ++kt) {
    const int cur = (kt - kt0) & 1;
    if (kt + 1 < kt1) stage(kt + 1, cur ^ 1);
    #pragma unroll
    for (int ks = 0; ks < 2; ++ks) {
      const int octd = (ks * 4 + (l >> 4)) ^ (l & 7);   // swizzled octet slot
      s16x8 af[4], bfr[2];
      #pragma unroll
      for (int mf = 0; mf < 4; ++mf)
        af[mf] = *(const s16x8*)((char*)Al[cur] +
            (wr * 64 + mf * 16 + (l & 15)) * 128 + octd * 16);
      #pragma unroll
      for (int nf = 0; nf < 2; ++nf)
        bfr[nf] = *(const s16x8*)((char*)Bl[cur] +
            (wc * 32 + nf * 16 + (l & 15)) * 128 + octd * 16);
      #pragma unroll
      for (int mf = 0; mf < 4; ++mf)
        #pragma unroll
        for (int nf = 0; nf < 2; ++nf)
          acc[mf][nf] = __builtin_amdgcn_mfma_f32_16x16x32_bf16(af[mf], bfr[nf], acc[mf][nf], 0, 0, 0);
    }
    __syncthreads();
  }

  #pragma unroll
  for (int mf = 0; mf < 4; ++mf) {
    #pragma unroll
    for (int i = 0; i < 4; ++i) {
      const int rloc = wr * 64 + mf * 16 + (l >> 4) * 4 + i;
      int grow; bool valid = true;
      if (GATHER) {
        const int bidx = mt * 128 + rloc;
        valid = bidx < cnt;
        grow = valid ? bucket[bidx] : 0;
      } else grow = mt * 128 + rloc;
      float srow = 0.f;
      if (EPI == 3) srow = valid ? p.sA[grow] : 0.f;
      if (EPI == 4) srow = p.sB[grow];
      #pragma unroll
      for (int nf = 0; nf < 2; ++nf) {
        const int col = nt * 64 + wc * 32 + nf * 16 + (l & 15);
        const size_t off = (size_t)grow * N + col;
        const float bc = first ? bias[col] : 0.f;
        if (EPI == 0) {
          if (valid) p.outh[off] = f2bf(acc[mf][nf][i] + bc);
        } else if (EPI == 1) {
          const float v = acc[mf][nf][i] + bc;
          const float gv = 0.5f * v * (1.0f + erff(v * 0.70710678f));
          if (valid) p.outh[off] = f2bf(gv);
        } else if (EPI == 2) {
          atomicAdd(&p.outf[off], acc[mf][nf][i] + bc + (first ? p.resid[off] : 0.f));
        } else if (EPI == 3) {
          if (valid) atomicAdd(&p.outf[off], (acc[mf][nf][i] + bc) * srow);
        } else if (EPI == 4) {
          atomicAdd(&p.outf[off], (acc[mf][nf][i] + bc) * srow +
                    (first ? p.resid[off] + p.aux[off] : 0.f));
        }
      }
    }
  }
}

// ---------------- Flash attention: 4 waves x 16 q-rows, KV tiles of 64 ----------------
__global__ __launch_bounds__(256, 2)
void attn_k(const short* __restrict__ qkv, short* __restrict__ ctx)
{
  __shared__ short Klds[64 * 64];
  __shared__ short Vlds[64 * 64];
  __shared__ short Plds[4 * 16 * 64];
  const int tid = threadIdx.x, l = tid & 63, w = tid >> 6;
  const int qt = blockIdx.x;
  const int bh = blockIdx.y;
  const int b = bh >> 4, h = bh & 15;
  const size_t tbase = (size_t)b * 1024;

  const int sq = qt * 64 + w * 16 + (l & 15);
  s16x8 qf[2];
  #pragma unroll
  for (int ks = 0; ks < 2; ++ks)
    qf[ks] = *(const s16x8*)(qkv + (tbase + sq) * 3072 + h * 64 + ks * 32 + (l >> 4) * 8);

  f32x4 o[4] = {};
  float mrow[4], lrow[4];
  #pragma unroll
  for (int i = 0; i < 4; ++i) { mrow[i] = -1e30f; lrow[i] = 0.f; }

  for (int kt = 0; kt < 16; ++kt) {
    #pragma unroll
    for (int i = 0; i < 2; ++i) {
      const int s = i * 256 + tid;
      const int r = s >> 3, c = s & 7, csrc = c ^ (r & 7);
      const short* gsrc = qkv + (tbase + kt * 64 + r) * 3072 + 1024 + h * 64 + csrc * 8;
      gload_lds16(gsrc, (char*)Klds + (i * 256 + (tid & 192)) * 16);
    }
    #pragma unroll
    for (int i = 0; i < 2; ++i) {
      const int kv0 = (i * 4 + w) * 8;
      s16x8 vv;
      #pragma unroll
      for (int j = 0; j < 8; ++j)
        vv[j] = qkv[(tbase + kt * 64 + kv0 + j) * 3072 + 2048 + h * 64 + l];
      *(s16x8*)((char*)Vlds + ((l * 128 + kv0 * 2) ^ ((l & 7) << 4))) = vv;
    }
    __syncthreads();

    f32x4 sv[4];
    #pragma unroll
    for (int nf = 0; nf < 4; ++nf) {
      f32x4 a = {0.f, 0.f, 0.f, 0.f};
      const int kv = nf * 16 + (l & 15);
      #pragma unroll
      for (int ks = 0; ks < 2; ++ks) {
        const s16x8 kb = *(const s16x8*)((char*)Klds +
            ((kv * 128 + (ks * 32 + (l >> 4) * 8) * 2) ^ ((kv & 7) << 4)));
        a = __builtin_amdgcn_mfma_f32_16x16x32_bf16(qf[ks], kb, a, 0, 0, 0);
      }
      sv[nf] = a * 0.125f;
    }
    float sc[4], ps[4];
    #pragma unroll
    for (int i = 0; i < 4; ++i) {
      float m = fmaxf(fmaxf(sv[0][i], sv[1][i]), fmaxf(sv[2][i], sv[3][i]));
      #pragma unroll
      for (int msk = 1; msk < 16; msk <<= 1) m = fmaxf(m, __shfl_xor(m, msk));
      const float mn = fmaxf(mrow[i], m);
      sc[i] = __expf(mrow[i] - mn);
      mrow[i] = mn;
      ps[i] = 0.f;
    }
    #pragma unroll
    for (int nf = 0; nf < 4; ++nf)
      #pragma unroll
      for (int i = 0; i < 4; ++i) {
        const float pp = __expf(sv[nf][i] - mrow[i]);
        sv[nf][i] = pp;
        ps[i] += pp;
      }
    #pragma unroll
    for (int i = 0; i < 4; ++i) {
      #pragma unroll
      for (int msk = 1; msk < 16; msk <<= 1) ps[i] += __shfl_xor(ps[i], msk);
      lrow[i] = lrow[i] * sc[i] + ps[i];
    }
    #pragma unroll
    for (int nf = 0; nf < 4; ++nf)
      #pragma unroll
      for (int i = 0; i < 4; ++i) o[nf][i] *= sc[i];

    char* pw = (char*)Plds + w * 2048;
    #pragma unroll
    for (int nf = 0; nf < 4; ++nf)
      #pragma unroll
      for (int i = 0; i < 4; ++i) {
        const int q = (l >> 4) * 4 + i;
        *(short*)(pw + ((q * 128 + (nf * 16 + (l & 15)) * 2) ^ ((q & 7) << 4))) = f2bf(sv[nf][i]);
      }
    __syncthreads();
    #pragma unroll
    for (int ks = 0; ks < 2; ++ks) {
      const s16x8 pa = *(const s16x8*)(pw +
          (((l & 15) * 128 + (ks * 32 + (l >> 4) * 8) * 2) ^ ((l & 7) << 4)));
      #pragma unroll
      for (int nf = 0; nf < 4; ++nf) {
        const int dh = nf * 16 + (l & 15);
        const s16x8 vb = *(const s16x8*)((char*)Vlds +
            ((dh * 128 + (ks * 32 + (l >> 4) * 8) * 2) ^ ((dh & 7) << 4)));
        o[nf] = __builtin_amdgcn_mfma_f32_16x16x32_bf16(pa, vb, o[nf], 0, 0, 0);
      }
    }
    __syncthreads();
  }
  #pragma unroll
  for (int i = 0; i < 4; ++i) {
    const float inv = 1.0f / lrow[i];
    const size_t t = tbase + qt * 64 + w * 16 + (l >> 4) * 4 + i;
    #pragma unroll
    for (int nf = 0; nf < 4; ++nf)
      ctx[t * 1024 + h * 64 + nf * 16 + (l & 15)] = f2bf(o[nf][i] * inv);
  }
}

extern "C" void kernel_launch(void* const* d_in, const int* in_sizes, int n_in,
                              void* d_out, int out_size, void* d_ws, size_t ws_size,
                              hipStream_t stream)
{
  const float* x    = (const float*)d_in[0];
  const float* ln1g = (const float*)d_in[1];
  const float* ln1b = (const float*)d_in[2];
  const float* Wqkv = (const float*)d_in[3];
  const float* bqkv = (const float*)d_in[4];
  const float* Wo   = (const float*)d_in[5];
  const float* bo   = (const float*)d_in[6];
  const float* ln2g = (const float*)d_in[7];
  const float* ln2b = (const float*)d_in[8];
  const float* gw   = (const float*)d_in[9];
  const float* W1   = (const float*)d_in[10];
  const float* b1   = (const float*)d_in[11];
  const float* W2   = (const float*)d_in[12];
  const float* b2   = (const float*)d_in[13];
  const float* rW1  = (const float*)d_in[14];
  const float* rb1  = (const float*)d_in[15];
  const float* rW2  = (const float*)d_in[16];
  const float* rb2  = (const float*)d_in[17];
  const float* cw   = (const float*)d_in[18];
  const float* cb   = (const float*)d_in[19];
  float* out = (float*)d_out;

  char* ws = (char*)d_ws;
  const size_t MB = 1024 * 1024;
  short* xn1    = (short*)(ws + 0);          // 4 MB
  short* qkv    = (short*)(ws + 4 * MB);     // 12 MB
  short* he     = (short*)(ws + 4 * MB);     // 16 MB (aliases qkv+ctx, dead by then)
  short* ctx    = (short*)(ws + 16 * MB);    // 4 MB
  float* x1     = (float*)(ws + 20 * MB);    // 8 MB
  short* xn2    = (short*)(ws + 28 * MB);    // 4 MB
  short* hr     = (short*)(ws + 32 * MB);    // 16 MB
  float* moe    = (float*)(ws + 48 * MB);    // 8 MB
  int*   counts = (int*)(ws + 56 * MB);
  int*   bucket = (int*)(ws + 56 * MB + 256);
  float* gs     = (float*)(ws + 56 * MB + 256 + 64 * 1024);
  float* c1     = (float*)(ws + 56 * MB + 256 + 64 * 1024 + 8192);
  // packed bf16 weight tiles (requires ws_size >= ~220 MB)
  short* Wqkvp  = (short*)(ws + 64 * MB);    // 6 MB
  short* Wop    = (short*)(ws + 70 * MB);    // 2 MB
  short* W1p    = (short*)(ws + 72 * MB);    // 64 MB
  short* W2p    = (short*)(ws + 136 * MB);   // 64 MB
  short* rW1p   = (short*)(ws + 200 * MB);   // 8 MB
  short* rW2p   = (short*)(ws + 208 * MB);   // 8 MB

  hipMemsetAsync(counts, 0, 8 * sizeof(int), stream);
  hipMemsetAsync(x1, 0, TOK * NDIM * sizeof(float), stream);
  hipMemsetAsync(moe, 0, TOK * NDIM * sizeof(float), stream);
  hipMemsetAsync(out, 0, TOK * NDIM * sizeof(float), stream);

  // --- weight packing (once per launch) ---
  PackP pk;
  pk = PackP{Wqkv, Wqkvp, 1024, 3072, 16}; pack_k<<<dim3(48 * 16, 1), 256, 0, stream>>>(pk);
  pk = PackP{Wo,   Wop,   1024, 1024, 16}; pack_k<<<dim3(16 * 16, 1), 256, 0, stream>>>(pk);
  pk = PackP{W1,   W1p,   1024, 4096, 16}; pack_k<<<dim3(64 * 16, 8), 256, 0, stream>>>(pk);
  pk = PackP{W2,   W2p,   4096, 1024, 64}; pack_k<<<dim3(16 * 64, 8), 256, 0, stream>>>(pk);
  pk = PackP{rW1,  rW1p,  1024, 4096, 16}; pack_k<<<dim3(64 * 16, 1), 256, 0, stream>>>(pk);
  pk = PackP{rW2,  rW2p,  4096, 1024, 64}; pack_k<<<dim3(16 * 64, 1), 256, 0, stream>>>(pk);

  ln_k<<<TOK, 256, 0, stream>>>(x, ln1g, ln1b, xn1);

  GemmP p{};
  p.A = xn1; p.Bp = Wqkvp; p.bias = bqkv; p.outh = qkv; p.N = 3072; p.K = 1024; p.ktc = 16;
  gemm_k<0, false><<<dim3(16 * 48), 256, 0, stream>>>(p);

  attn_k<<<dim3(16, 32), 256, 0, stream>>>(qkv, ctx);

  // x1 = x + ctx @ Wo + bo  (split-K = 2)
  p = GemmP{};
  p.A = ctx; p.Bp = Wop; p.bias = bo; p.outf = x1; p.resid = x; p.N = 1024; p.K = 1024; p.ktc = 8;
  gemm_k<2, false><<<dim3(16 * 16, 1, 2), 256, 0, stream>>>(p);

  ln_k<<<TOK, 256, 0, stream>>>(x1, ln2g, ln2b, xn2);
  gate_k<<<TOK / 4, 256, 0, stream>>>(x1, ln2g, ln2b, gw, cw, cb, counts, bucket, gs, c1);

  // he = gelu(gather(xn2) @ W1 + b1)
  p = GemmP{};
  p.A = xn2; p.Bp = W1p; p.bias = b1; p.outh = he; p.N = 4096; p.K = 1024; p.ktc = 16;
  p.bucket = bucket; p.counts = counts;
  gemm_k<1, true><<<dim3(16 * 64, 8), 256, 0, stream>>>(p);

  // moe = (he @ W2 + b2) * gs  (split-K = 4)
  p = GemmP{};
  p.A = he; p.Bp = W2p; p.bias = b2; p.outf = moe; p.sA = gs; p.N = 1024; p.K = 4096; p.ktc = 16;
  p.bucket = bucket; p.counts = counts;
  gemm_k<3, true><<<dim3(16 * 16, 8, 4), 256, 0, stream>>>(p);

  // hr = gelu(xn2 @ rW1 + rb1)
  p = GemmP{};
  p.A = xn2; p.Bp = rW1p; p.bias = rb1; p.outh = hr; p.N = 4096; p.K = 1024; p.ktc = 16;
  gemm_k<1, false><<<dim3(16 * 64), 256, 0, stream>>>(p);

  // out = x1 + moe + (hr @ rW2 + rb2) * c1  (split-K = 4)
  p = GemmP{};
  p.A = hr; p.Bp = rW2p; p.bias = rb2; p.outf = out; p.resid = x1; p.aux = moe; p.sB = c1;
  p.N = 1024; p.K = 4096; p.ktc = 16;
  gemm_k<4, false><<<dim3(16 * 16, 1, 4), 256, 0, stream>>>(p);
}

// Round 5
// 488.217 us; speedup vs baseline: 1.5013x; 1.0472x over previous
//
#include <hip/hip_runtime.h>
#include <math.h>

#define TOK 2048
#define NDIM 1024

typedef __attribute__((ext_vector_type(4))) float f32x4;
typedef __attribute__((ext_vector_type(8))) short s16x8;
typedef __attribute__((ext_vector_type(4))) short s16x4;

__device__ __forceinline__ short f2bf(float x) {
  unsigned int u = __builtin_bit_cast(unsigned int, x);
  unsigned int r = (u + 0x7fffu + ((u >> 16) & 1u)) >> 16;
  return (short)r;
}
__device__ __forceinline__ void gload_lds16(const void* g, void* l) {
  __builtin_amdgcn_global_load_lds((const __attribute__((address_space(1))) void*)g,
                                   (__attribute__((address_space(3))) void*)l, 16, 0, 0);
}

// ---------------- Weight pack: [K][N] fp32 -> tiles [nt][kt] of 8KB bf16 ----------------
// Block covers [64k][256n]; coalesced f32x4 row reads; writes 4 tiles.
// Tile chunk at byte (col*128 + od*16) holds W[k0+o*8+j][n0+col], o = od ^ (col&7).
struct PackP { const float* src; short* dst; int K, N, nkt; };
__global__ __launch_bounds__(256)
void pack_k(PackP p)
{
  __shared__ short T[64][264];
  const int nkt = p.nkt;
  const int cb = blockIdx.x / nkt, kt = blockIdx.x % nkt;
  const int ntn = p.N >> 6;
  const float* src = p.src + (size_t)blockIdx.y * p.K * p.N + (size_t)(kt * 64) * p.N + cb * 256;
  const int t = threadIdx.x;
  #pragma unroll
  for (int i = 0; i < 16; ++i) {
    const int r = i * 4 + (t >> 6);
    const f32x4 v = *(const f32x4*)(src + (size_t)r * p.N + (t & 63) * 4);
    short* d = &T[r][(t & 63) * 4];
    d[0] = f2bf(v[0]); d[1] = f2bf(v[1]); d[2] = f2bf(v[2]); d[3] = f2bf(v[3]);
  }
  __syncthreads();
  #pragma unroll
  for (int j = 0; j < 4; ++j) {
    short* dst = p.dst + ((size_t)(blockIdx.y * ntn + cb * 4 + j) * nkt + kt) * 4096 + t * 16;
    s16x8 v0, v1;
    #pragma unroll
    for (int jj = 0; jj < 2; ++jj) {
      const int chunk = t * 2 + jj;
      const int col = chunk >> 3, od = chunk & 7, o = od ^ (col & 7);
      #pragma unroll
      for (int kk = 0; kk < 8; ++kk) {
        const short vv = T[o * 8 + kk][j * 64 + col];
        if (jj == 0) v0[kk] = vv; else v1[kk] = vv;
      }
    }
    *(s16x8*)dst = v0;
    *(s16x8*)(dst + 8) = v1;
  }
}

// ---------------- LayerNorm: fp32 in -> bf16 out ----------------
__global__ __launch_bounds__(256)
void ln_k(const float* __restrict__ x, const float* __restrict__ g,
          const float* __restrict__ bb, short* __restrict__ out)
{
  const int row = blockIdx.x, tid = threadIdx.x;
  const f32x4 xv = *(const f32x4*)(x + (size_t)row * NDIM + tid * 4);
  float s = xv[0] + xv[1] + xv[2] + xv[3];
  float s2 = xv[0]*xv[0] + xv[1]*xv[1] + xv[2]*xv[2] + xv[3]*xv[3];
  #pragma unroll
  for (int m = 1; m < 64; m <<= 1) { s += __shfl_xor(s, m); s2 += __shfl_xor(s2, m); }
  __shared__ float red[8];
  const int w = tid >> 6, l = tid & 63;
  if (l == 0) { red[w] = s; red[4 + w] = s2; }
  __syncthreads();
  s = red[0] + red[1] + red[2] + red[3];
  s2 = red[4] + red[5] + red[6] + red[7];
  const float mean = s * (1.0f / NDIM);
  const float var = s2 * (1.0f / NDIM) - mean * mean;
  const float rstd = rsqrtf(var + 1e-5f);
  const f32x4 gv = *(const f32x4*)(g + tid * 4);
  const f32x4 bv = *(const f32x4*)(bb + tid * 4);
  s16x4 ov;
  #pragma unroll
  for (int j = 0; j < 4; ++j) ov[j] = f2bf((xv[j] - mean) * rstd * gv[j] + bv[j]);
  *(s16x4*)(out + (size_t)row * NDIM + tid * 4) = ov;
}

// ---------------- Gate: fp32 LN recompute + gate/coef softmax + buckets ----------------
__global__ __launch_bounds__(256)
void gate_k(const float* __restrict__ x1, const float* __restrict__ g,
            const float* __restrict__ bb, const float* __restrict__ gw,
            const float* __restrict__ cw, const float* __restrict__ cb,
            int* __restrict__ counts, int* __restrict__ bucket,
            float* __restrict__ gs, float* __restrict__ c1o)
{
  const int tid = threadIdx.x, l = tid & 63, w = tid >> 6;
  const int t = blockIdx.x * 4 + w;
  f32x4 xv[4];
  #pragma unroll
  for (int it = 0; it < 4; ++it)
    xv[it] = *(const f32x4*)(x1 + (size_t)t * NDIM + it * 256 + l * 4);
  float s = 0.f, s2 = 0.f;
  #pragma unroll
  for (int it = 0; it < 4; ++it)
    #pragma unroll
    for (int j = 0; j < 4; ++j) { s += xv[it][j]; s2 += xv[it][j] * xv[it][j]; }
  #pragma unroll
  for (int m = 1; m < 64; m <<= 1) { s += __shfl_xor(s, m); s2 += __shfl_xor(s2, m); }
  const float mean = s * (1.0f / NDIM);
  const float rstd = rsqrtf(s2 * (1.0f / NDIM) - mean * mean + 1e-5f);
  float acc[10];
  #pragma unroll
  for (int j = 0; j < 10; ++j) acc[j] = 0.f;
  #pragma unroll
  for (int it = 0; it < 4; ++it) {
    #pragma unroll
    for (int j = 0; j < 4; ++j) {
      const int d0 = it * 256 + l * 4 + j;
      const float xn = (xv[it][j] - mean) * rstd * g[d0] + bb[d0];
      const f32x4 g0 = *(const f32x4*)(gw + (size_t)d0 * 8);
      const f32x4 g1 = *(const f32x4*)(gw + (size_t)d0 * 8 + 4);
      #pragma unroll
      for (int q = 0; q < 4; ++q) { acc[q] += xn * g0[q]; acc[4 + q] += xn * g1[q]; }
      acc[8] += xn * cw[d0 * 2]; acc[9] += xn * cw[d0 * 2 + 1];
    }
  }
  #pragma unroll
  for (int j = 0; j < 10; ++j)
    #pragma unroll
    for (int m = 1; m < 64; m <<= 1) acc[j] += __shfl_xor(acc[j], m);
  if (l == 0) {
    int best = 0; float mx = acc[0];
    #pragma unroll
    for (int e = 1; e < 8; ++e) if (acc[e] > mx) { mx = acc[e]; best = e; }
    float se = 0.f;
    #pragma unroll
    for (int e = 0; e < 8; ++e) se += __expf(acc[e] - mx);
    const float gate_val = 1.0f / se;
    const float l0 = acc[8] + cb[0], l1 = acc[9] + cb[1];
    const float cmx = fmaxf(l0, l1);
    const float e0 = __expf(l0 - cmx), e1 = __expf(l1 - cmx);
    const float inv = 1.0f / (e0 + e1);
    const int pos = atomicAdd(&counts[best], 1);
    bucket[best * TOK + pos] = t;
    gs[t] = gate_val * e0 * inv;
    c1o[t] = e1 * inv;
  }
}

// ---------------- bf16 MFMA GEMM, 128x64 tile, BK=64, counted-vmcnt dbuf ----------------
// MODE 0: dense, store bf16 (QKV)
// MODE 1: dense split-K, atomic x1 = x + acc + bias (Wo)
// MODE 2: 9-expert up-proj (e<8 gather->he, e==8 identity->hr), GELU bf16
// MODE 3: 9-expert down-proj split-K, atomic out += (acc+bias)*scale (+x1 on e==8,z==0)
struct GemmP {
  const short* A; const short* A2; const short* Bp; const short* Bp2;
  const float* bias; const float* bias2;
  short* outh; short* outh2; float* outf;
  const float* resid; const float* gs; const float* c1;
  const int* bucket; const int* counts;
  int N, K, ktc;
};

template<int MODE>
__global__ __launch_bounds__(256, 3)
void gemm_k(GemmP p)
{
  __shared__ short Al[2][8192];  // 16KB each: [row128][octd8][16B] xor-swizzled
  __shared__ short Bl[2][4096];  // 8KB each:  [col64][octd8][16B] xor-swizzled (packed)
  const int tid = threadIdx.x;
  const int l = tid & 63, w = tid >> 6;
  const int wr = w >> 1, wc = w & 1;
  const int ntn = p.N >> 6, nkt = p.K >> 6;
  const int mt = blockIdx.x / ntn;
  const int nt = blockIdx.x % ntn;
  const int z = blockIdx.z;
  const bool first = (z == 0);
  const int K = p.K, N = p.N;

  int e = 0, cnt = TOK;
  const int* bucket = nullptr;
  if (MODE >= 2) {
    e = blockIdx.y;
    if (e < 8) {
      cnt = p.counts[e];
      if (mt * 128 >= cnt) return;
      bucket = p.bucket + e * TOK;
    }
  }
  const short* Abase = (MODE == 3 && e == 8) ? p.A2 : p.A;
  const float* bias = (MODE >= 2) ? (e < 8 ? p.bias + (size_t)e * N : p.bias2) : p.bias;
  const short* btile = (MODE >= 2)
      ? (e < 8 ? p.Bp + ((size_t)(e * ntn + nt) * nkt) * 4096
               : p.Bp2 + ((size_t)nt * nkt) * 4096)
      : p.Bp + ((size_t)nt * nkt) * 4096;

  // A staging: chunk c = i*256+tid; row = c>>3, src octet = (tid&7)^(row&7)
  const short* aptr[4];
  #pragma unroll
  for (int i = 0; i < 4; ++i) {
    const int rl = (i * 256 + tid) >> 3;
    int row;
    if (bucket) {
      const int bidx = mt * 128 + rl;
      row = bucket[bidx < cnt ? bidx : mt * 128];
    } else row = mt * 128 + rl;
    aptr[i] = Abase + (size_t)row * K + ((tid & 7) ^ (rl & 7)) * 8;
  }

  const int kt0 = z * p.ktc, kt1 = kt0 + p.ktc;

  auto stage = [&](int kt, int buf) {  // 6 global_load_lds per thread
    const short* bsrc = btile + kt * 4096;
    #pragma unroll
    for (int j = 0; j < 2; ++j)
      gload_lds16(bsrc + (j * 256 + tid) * 8, (char*)Bl[buf] + (j * 256 + (tid & 192)) * 16);
    #pragma unroll
    for (int i = 0; i < 4; ++i)
      gload_lds16(aptr[i] + kt * 64, (char*)Al[buf] + (i * 256 + (tid & 192)) * 16);
  };

  f32x4 acc[4][2] = {};
  stage(kt0, 0);
  for (int kt = kt0; kt < kt1; ++kt) {
    const int cur = (kt - kt0) & 1;
    if (kt + 1 < kt1) {
      stage(kt + 1, cur ^ 1);
      asm volatile("s_waitcnt vmcnt(6)" ::: "memory");  // cur's 6 done, next's 6 in flight
    } else {
      asm volatile("s_waitcnt vmcnt(0)" ::: "memory");
    }
    __builtin_amdgcn_s_barrier();
    #pragma unroll
    for (int ks = 0; ks < 2; ++ks) {
      const int octd = (ks * 4 + (l >> 4)) ^ (l & 7);
      s16x8 af[4], bfr[2];
      #pragma unroll
      for (int mf = 0; mf < 4; ++mf)
        af[mf] = *(const s16x8*)((char*)Al[cur] +
            (wr * 64 + mf * 16 + (l & 15)) * 128 + octd * 16);
      #pragma unroll
      for (int nf = 0; nf < 2; ++nf)
        bfr[nf] = *(const s16x8*)((char*)Bl[cur] +
            (wc * 32 + nf * 16 + (l & 15)) * 128 + octd * 16);
      #pragma unroll
      for (int mf = 0; mf < 4; ++mf)
        #pragma unroll
        for (int nf = 0; nf < 2; ++nf)
          acc[mf][nf] = __builtin_amdgcn_mfma_f32_16x16x32_bf16(af[mf], bfr[nf], acc[mf][nf], 0, 0, 0);
    }
    asm volatile("" ::: "memory");
    __builtin_amdgcn_s_barrier();  // all waves done reading cur before it is restaged
  }

  short* oh = (MODE == 2) ? (e < 8 ? p.outh : p.outh2) : p.outh;
  #pragma unroll
  for (int mf = 0; mf < 4; ++mf) {
    #pragma unroll
    for (int i = 0; i < 4; ++i) {
      const int rloc = wr * 64 + mf * 16 + (l >> 4) * 4 + i;
      int grow; bool valid = true;
      if (bucket) {
        const int bidx = mt * 128 + rloc;
        valid = bidx < cnt;
        grow = valid ? bucket[bidx] : 0;
      } else grow = mt * 128 + rloc;
      float srow = 1.f;
      if (MODE == 3) srow = (e < 8) ? (valid ? p.gs[grow] : 0.f) : p.c1[grow];
      #pragma unroll
      for (int nf = 0; nf < 2; ++nf) {
        const int col = nt * 64 + wc * 32 + nf * 16 + (l & 15);
        const size_t off = (size_t)grow * N + col;
        const float bc = first ? bias[col] : 0.f;
        if (MODE == 0) {
          oh[off] = f2bf(acc[mf][nf][i] + bc);
        } else if (MODE == 1) {
          atomicAdd(&p.outf[off], acc[mf][nf][i] + bc + (first ? p.resid[off] : 0.f));
        } else if (MODE == 2) {
          const float v = acc[mf][nf][i] + bc;
          const float gv = 0.5f * v * (1.0f + erff(v * 0.70710678f));
          if (valid) oh[off] = f2bf(gv);
        } else if (MODE == 3) {
          if (valid)
            atomicAdd(&p.outf[off], (acc[mf][nf][i] + bc) * srow +
                      ((e == 8 && first) ? p.resid[off] : 0.f));
        }
      }
    }
  }
}

// ---------------- Flash attention: 4 waves x 16 q-rows, KV tiles of 64 ----------------
__global__ __launch_bounds__(256, 2)
void attn_k(const short* __restrict__ qkv, short* __restrict__ ctx)
{
  __shared__ short Klds[64 * 64];
  __shared__ short Vlds[64 * 64];
  __shared__ short Plds[4 * 16 * 64];
  const int tid = threadIdx.x, l = tid & 63, w = tid >> 6;
  const int qt = blockIdx.x;
  const int bh = blockIdx.y;
  const int b = bh >> 4, h = bh & 15;
  const size_t tbase = (size_t)b * 1024;

  const int sq = qt * 64 + w * 16 + (l & 15);
  s16x8 qf[2];
  #pragma unroll
  for (int ks = 0; ks < 2; ++ks)
    qf[ks] = *(const s16x8*)(qkv + (tbase + sq) * 3072 + h * 64 + ks * 32 + (l >> 4) * 8);

  f32x4 o[4] = {};
  float mrow[4], lrow[4];
  #pragma unroll
  for (int i = 0; i < 4; ++i) { mrow[i] = -1e30f; lrow[i] = 0.f; }

  for (int kt = 0; kt < 16; ++kt) {
    #pragma unroll
    for (int i = 0; i < 2; ++i) {
      const int s = i * 256 + tid;
      const int r = s >> 3, c = s & 7, csrc = c ^ (r & 7);
      const short* gsrc = qkv + (tbase + kt * 64 + r) * 3072 + 1024 + h * 64 + csrc * 8;
      gload_lds16(gsrc, (char*)Klds + (i * 256 + (tid & 192)) * 16);
    }
    #pragma unroll
    for (int i = 0; i < 2; ++i) {
      const int kv0 = (i * 4 + w) * 8;
      s16x8 vv;
      #pragma unroll
      for (int j = 0; j < 8; ++j)
        vv[j] = qkv[(tbase + kt * 64 + kv0 + j) * 3072 + 2048 + h * 64 + l];
      *(s16x8*)((char*)Vlds + ((l * 128 + kv0 * 2) ^ ((l & 7) << 4))) = vv;
    }
    __syncthreads();

    f32x4 sv[4];
    #pragma unroll
    for (int nf = 0; nf < 4; ++nf) {
      f32x4 a = {0.f, 0.f, 0.f, 0.f};
      const int kv = nf * 16 + (l & 15);
      #pragma unroll
      for (int ks = 0; ks < 2; ++ks) {
        const s16x8 kb = *(const s16x8*)((char*)Klds +
            ((kv * 128 + (ks * 32 + (l >> 4) * 8) * 2) ^ ((kv & 7) << 4)));
        a = __builtin_amdgcn_mfma_f32_16x16x32_bf16(qf[ks], kb, a, 0, 0, 0);
      }
      sv[nf] = a * 0.125f;
    }
    float sc[4], ps[4];
    #pragma unroll
    for (int i = 0; i < 4; ++i) {
      float m = fmaxf(fmaxf(sv[0][i], sv[1][i]), fmaxf(sv[2][i], sv[3][i]));
      #pragma unroll
      for (int msk = 1; msk < 16; msk <<= 1) m = fmaxf(m, __shfl_xor(m, msk));
      const float mn = fmaxf(mrow[i], m);
      sc[i] = __expf(mrow[i] - mn);
      mrow[i] = mn;
      ps[i] = 0.f;
    }
    #pragma unroll
    for (int nf = 0; nf < 4; ++nf)
      #pragma unroll
      for (int i = 0; i < 4; ++i) {
        const float pp = __expf(sv[nf][i] - mrow[i]);
        sv[nf][i] = pp;
        ps[i] += pp;
      }
    #pragma unroll
    for (int i = 0; i < 4; ++i) {
      #pragma unroll
      for (int msk = 1; msk < 16; msk <<= 1) ps[i] += __shfl_xor(ps[i], msk);
      lrow[i] = lrow[i] * sc[i] + ps[i];
    }
    #pragma unroll
    for (int nf = 0; nf < 4; ++nf)
      #pragma unroll
      for (int i = 0; i < 4; ++i) o[nf][i] *= sc[i];

    char* pw = (char*)Plds + w * 2048;
    #pragma unroll
    for (int nf = 0; nf < 4; ++nf)
      #pragma unroll
      for (int i = 0; i < 4; ++i) {
        const int q = (l >> 4) * 4 + i;
        *(short*)(pw + ((q * 128 + (nf * 16 + (l & 15)) * 2) ^ ((q & 7) << 4))) = f2bf(sv[nf][i]);
      }
    __syncthreads();
    #pragma unroll
    for (int ks = 0; ks < 2; ++ks) {
      const s16x8 pa = *(const s16x8*)(pw +
          (((l & 15) * 128 + (ks * 32 + (l >> 4) * 8) * 2) ^ ((l & 7) << 4)));
      #pragma unroll
      for (int nf = 0; nf < 4; ++nf) {
        const int dh = nf * 16 + (l & 15);
        const s16x8 vb = *(const s16x8*)((char*)Vlds +
            ((dh * 128 + (ks * 32 + (l >> 4) * 8) * 2) ^ ((dh & 7) << 4)));
        o[nf] = __builtin_amdgcn_mfma_f32_16x16x32_bf16(pa, vb, o[nf], 0, 0, 0);
      }
    }
    __syncthreads();
  }
  #pragma unroll
  for (int i = 0; i < 4; ++i) {
    const float inv = 1.0f / lrow[i];
    const size_t t = tbase + qt * 64 + w * 16 + (l >> 4) * 4 + i;
    #pragma unroll
    for (int nf = 0; nf < 4; ++nf)
      ctx[t * 1024 + h * 64 + nf * 16 + (l & 15)] = f2bf(o[nf][i] * inv);
  }
}

extern "C" void kernel_launch(void* const* d_in, const int* in_sizes, int n_in,
                              void* d_out, int out_size, void* d_ws, size_t ws_size,
                              hipStream_t stream)
{
  const float* x    = (const float*)d_in[0];
  const float* ln1g = (const float*)d_in[1];
  const float* ln1b = (const float*)d_in[2];
  const float* Wqkv = (const float*)d_in[3];
  const float* bqkv = (const float*)d_in[4];
  const float* Wo   = (const float*)d_in[5];
  const float* bo   = (const float*)d_in[6];
  const float* ln2g = (const float*)d_in[7];
  const float* ln2b = (const float*)d_in[8];
  const float* gw   = (const float*)d_in[9];
  const float* W1   = (const float*)d_in[10];
  const float* b1   = (const float*)d_in[11];
  const float* W2   = (const float*)d_in[12];
  const float* b2   = (const float*)d_in[13];
  const float* rW1  = (const float*)d_in[14];
  const float* rb1  = (const float*)d_in[15];
  const float* rW2  = (const float*)d_in[16];
  const float* rb2  = (const float*)d_in[17];
  const float* cw   = (const float*)d_in[18];
  const float* cb   = (const float*)d_in[19];
  float* out = (float*)d_out;

  char* ws = (char*)d_ws;
  const size_t MB = 1024 * 1024;
  short* xn1    = (short*)(ws + 0);          // 4 MB
  short* qkv    = (short*)(ws + 4 * MB);     // 12 MB
  short* he     = (short*)(ws + 4 * MB);     // 16 MB (aliases qkv+ctx, dead by then)
  short* ctx    = (short*)(ws + 16 * MB);    // 4 MB
  float* x1     = (float*)(ws + 20 * MB);    // 8 MB
  short* xn2    = (short*)(ws + 28 * MB);    // 4 MB
  short* hr     = (short*)(ws + 32 * MB);    // 16 MB
  int*   counts = (int*)(ws + 56 * MB);
  int*   bucket = (int*)(ws + 56 * MB + 256);
  float* gs     = (float*)(ws + 56 * MB + 256 + 64 * 1024);
  float* c1     = (float*)(ws + 56 * MB + 256 + 64 * 1024 + 8192);
  short* Wqkvp  = (short*)(ws + 64 * MB);    // 6 MB
  short* Wop    = (short*)(ws + 70 * MB);    // 2 MB
  short* W1p    = (short*)(ws + 72 * MB);    // 64 MB
  short* W2p    = (short*)(ws + 136 * MB);   // 64 MB
  short* rW1p   = (short*)(ws + 200 * MB);   // 8 MB
  short* rW2p   = (short*)(ws + 208 * MB);   // 8 MB

  hipMemsetAsync(counts, 0, 8 * sizeof(int), stream);
  hipMemsetAsync(x1, 0, TOK * NDIM * sizeof(float), stream);
  hipMemsetAsync(out, 0, TOK * NDIM * sizeof(float), stream);

  // --- weight packing ---
  PackP pk;
  pk = PackP{Wqkv, Wqkvp, 1024, 3072, 16}; pack_k<<<dim3(12 * 16, 1), 256, 0, stream>>>(pk);
  pk = PackP{Wo,   Wop,   1024, 1024, 16}; pack_k<<<dim3(4 * 16, 1), 256, 0, stream>>>(pk);
  pk = PackP{W1,   W1p,   1024, 4096, 16}; pack_k<<<dim3(16 * 16, 8), 256, 0, stream>>>(pk);
  pk = PackP{W2,   W2p,   4096, 1024, 64}; pack_k<<<dim3(4 * 64, 8), 256, 0, stream>>>(pk);
  pk = PackP{rW1,  rW1p,  1024, 4096, 16}; pack_k<<<dim3(16 * 16, 1), 256, 0, stream>>>(pk);
  pk = PackP{rW2,  rW2p,  4096, 1024, 64}; pack_k<<<dim3(4 * 64, 1), 256, 0, stream>>>(pk);

  ln_k<<<TOK, 256, 0, stream>>>(x, ln1g, ln1b, xn1);

  // qkv = xn1 @ Wqkv + bqkv
  GemmP p{};
  p.A = xn1; p.Bp = Wqkvp; p.bias = bqkv; p.outh = qkv; p.N = 3072; p.K = 1024; p.ktc = 16;
  gemm_k<0><<<dim3(16 * 48), 256, 0, stream>>>(p);

  attn_k<<<dim3(16, 32), 256, 0, stream>>>(qkv, ctx);

  // x1 = x + ctx @ Wo + bo  (split-K = 2)
  p = GemmP{};
  p.A = ctx; p.Bp = Wop; p.bias = bo; p.outf = x1; p.resid = x; p.N = 1024; p.K = 1024; p.ktc = 8;
  gemm_k<1><<<dim3(16 * 16, 1, 2), 256, 0, stream>>>(p);

  ln_k<<<TOK, 256, 0, stream>>>(x1, ln2g, ln2b, xn2);
  gate_k<<<TOK / 4, 256, 0, stream>>>(x1, ln2g, ln2b, gw, cw, cb, counts, bucket, gs, c1);

  // fused up-proj: e<8 he = gelu(gather(xn2)@W1+b1); e==8 hr = gelu(xn2@rW1+rb1)
  p = GemmP{};
  p.A = xn2; p.Bp = W1p; p.Bp2 = rW1p; p.bias = b1; p.bias2 = rb1;
  p.outh = he; p.outh2 = hr; p.N = 4096; p.K = 1024; p.ktc = 16;
  p.bucket = bucket; p.counts = counts;
  gemm_k<2><<<dim3(16 * 64, 9), 256, 0, stream>>>(p);

  // fused down-proj (split-K = 4): out += (he@W2+b2)*gs | (hr@rW2+rb2)*c1 + x1
  p = GemmP{};
  p.A = he; p.A2 = hr; p.Bp = W2p; p.Bp2 = rW2p; p.bias = b2; p.bias2 = rb2;
  p.outf = out; p.resid = x1; p.gs = gs; p.c1 = c1; p.N = 1024; p.K = 4096; p.ktc = 16;
  p.bucket = bucket; p.counts = counts;
  gemm_k<3><<<dim3(16 * 16, 9, 4), 256, 0, stream>>>(p);
}